// Round 1
// baseline (151.969 us; speedup 1.0000x reference)
//
#include <hip/hip_runtime.h>

#define LOG2E 1.44269504088896340f

typedef __attribute__((ext_vector_type(8)))  short s8v;
typedef __attribute__((ext_vector_type(4)))  short s4v;
typedef __attribute__((ext_vector_type(16))) float f16v;

__device__ __forceinline__ unsigned short f2bf(float f) {
  union { float f; unsigned u; } v; v.f = f;
  unsigned r = v.u + 0x7FFFu + ((v.u >> 16) & 1u);
  return (unsigned short)(r >> 16);
}
__device__ __forceinline__ unsigned pack2bf(float a, float b) {
  return (unsigned)f2bf(a) | ((unsigned)f2bf(b) << 16);
}

// ---------------- GroupNorm (q path): 1 block per (n, group) ----------------
__global__ __launch_bounds__(256) void gn_apply_k(
    const float* __restrict__ x, const float* __restrict__ gamma,
    const float* __restrict__ beta, float* __restrict__ y)
{
  int blk = blockIdx.x; int n = blk >> 5, g = blk & 31;
  size_t base = (size_t)(n * 128 + g * 4) * 4096;
  const float4* x4 = (const float4*)(x + base);
  float4* y4 = (float4*)(y + base);
  int t = threadIdx.x;
  __shared__ float rs[256], rq[256];
  float s = 0.f, ss = 0.f;
  for (int i = t; i < 4096; i += 256) {
    float4 v = x4[i];
    s  += v.x + v.y + v.z + v.w;
    ss += v.x * v.x + v.y * v.y + v.z * v.z + v.w * v.w;
  }
  rs[t] = s; rq[t] = ss; __syncthreads();
  for (int o = 128; o > 0; o >>= 1) {
    if (t < o) { rs[t] += rs[t + o]; rq[t] += rq[t + o]; }
    __syncthreads();
  }
  float mu   = rs[0] * (1.f / 16384.f);
  float var  = rq[0] * (1.f / 16384.f) - mu * mu;
  float rstd = rsqrtf(var + 1e-5f);
  for (int i = t; i < 4096; i += 256) {
    float4 v = x4[i];
    int c = g * 4 + (i >> 10);
    float ga = gamma[c] * rstd;
    float be = beta[c] - mu * ga;
    float4 o4;
    o4.x = v.x * ga + be; o4.y = v.y * ga + be;
    o4.z = v.z * ga + be; o4.w = v.w * ga + be;
    y4[i] = o4;
  }
}

// ------------- avgpool2 + double GroupNorm (k/v path): 1 block per (n,g) -------------
__global__ __launch_bounds__(256) void pool_gn2_k(
    const float* __restrict__ x,
    const float* __restrict__ g1, const float* __restrict__ b1,
    const float* __restrict__ g2, const float* __restrict__ b2,
    float* __restrict__ y)
{
  __shared__ float buf[4096];
  __shared__ float red[256], rq[256];
  int blk = blockIdx.x; int n = blk >> 5, g = blk & 31;
  int t = threadIdx.x;
  float s = 0.f, ss = 0.f;
  for (int i = t; i < 4096; i += 256) {
    int cl = i >> 10, p = i & 1023;
    int py = p >> 5, px = p & 31;
    const float* xb = x + (size_t)(n * 128 + g * 4 + cl) * 4096 + py * 128;
    float2 a = ((const float2*)xb)[px];
    float2 b = ((const float2*)(xb + 64))[px];
    float v = 0.25f * (a.x + a.y + b.x + b.y);
    buf[i] = v; s += v; ss += v * v;
  }
  red[t] = s; rq[t] = ss; __syncthreads();
  for (int o = 128; o > 0; o >>= 1) {
    if (t < o) { red[t] += red[t + o]; rq[t] += rq[t + o]; }
    __syncthreads();
  }
  float mu   = red[0] * (1.f / 4096.f);
  float rstd = rsqrtf(rq[0] * (1.f / 4096.f) - mu * mu + 1e-5f);
  __syncthreads();
  s = 0.f; ss = 0.f;
  for (int i = t; i < 4096; i += 256) {
    int c = g * 4 + (i >> 10);
    float v = (buf[i] - mu) * rstd * g1[c] + b1[c];
    buf[i] = v; s += v; ss += v * v;
  }
  red[t] = s; rq[t] = ss; __syncthreads();
  for (int o = 128; o > 0; o >>= 1) {
    if (t < o) { red[t] += red[t + o]; rq[t] += rq[t + o]; }
    __syncthreads();
  }
  float mu2   = red[0] * (1.f / 4096.f);
  float rstd2 = rsqrtf(rq[0] * (1.f / 4096.f) - mu2 * mu2 + 1e-5f);
  for (int i = t; i < 4096; i += 256) {
    int cl = i >> 10, p = i & 1023;
    int c = g * 4 + cl;
    y[(size_t)(n * 128 + c) * 1024 + p] = (buf[i] - mu2) * rstd2 * g2[c] + b2[c];
  }
}

// ------------- conv1x1 (single bf16 MFMA) -> head-layout bf16 out -------------
// x: [N][128][S] f32.  out: [N*4][S][32] bf16 (u16).  TS=128 spatial per block.
__global__ __launch_bounds__(256) void conv1x1_k(
    const float* __restrict__ x, const float* __restrict__ W,
    const float* __restrict__ bias, unsigned short* __restrict__ po,
    int S, float outScale)
{
  __shared__ __align__(16) unsigned short smem[32768]; // 64KB: Wsw 32K | xsw 32K ; reused as ot
  unsigned short* Wsw = smem;
  unsigned short* xsw = smem + 16384;
  int t = threadIdx.x;
  int spb = S >> 7;
  int n  = blockIdx.x / spb;
  int s0 = (blockIdx.x % spb) << 7;

  // stage W (bf16, 16B-block swizzled: block = o*16 + ((c>>3) ^ (o&7)))
  #pragma unroll
  for (int k = 0; k < 16; ++k) {
    int f4 = t + (k << 8);
    int o = f4 >> 5, cq = f4 & 31;
    float4 wq = *(const float4*)(W + (size_t)o * 128 + cq * 4);
    s4v hv;
    hv[0] = (short)f2bf(wq.x); hv[1] = (short)f2bf(wq.y);
    hv[2] = (short)f2bf(wq.z); hv[3] = (short)f2bf(wq.w);
    *(s4v*)(Wsw + (o * 16 + ((cq >> 1) ^ (o & 7))) * 8 + (cq & 1) * 4) = hv;
  }
  // stage x (bf16, frag-major: block = (c>>3)*128 + s, elem = c&7)
  int sl = t & 127, coh = t >> 7;
  for (int co = coh; co < 16; co += 2) {
    const float* xb = x + (size_t)(n * 128 + co * 8) * S + s0 + sl;
    union { unsigned short u[8]; s8v v; } xv;
    #pragma unroll
    for (int e = 0; e < 8; ++e) xv.u[e] = f2bf(xb[(size_t)e * S]);
    *(s8v*)(xsw + (co * 128 + sl) * 8) = xv.v;
  }
  __syncthreads();

  int lane = t & 63, w = t >> 6;
  int l31 = lane & 31, h = lane >> 5;
  int wo = (w & 1) << 6, wsp = (w >> 1) << 6;
  f16v acc00 = {}, acc01 = {}, acc10 = {}, acc11 = {};
  #pragma unroll
  for (int reg = 0; reg < 16; ++reg) {
    int rm = (reg & 3) + ((reg >> 2) << 3) + (h << 2);
    float b0 = bias[wo + rm], b1 = bias[wo + 32 + rm];
    acc00[reg] = b0; acc01[reg] = b0; acc10[reg] = b1; acc11[reg] = b1;
  }
  const s8v* Wv = (const s8v*)Wsw;
  const s8v* Xv = (const s8v*)xsw;
  int o0 = wo + l31, o1 = wo + 32 + l31;
  #pragma unroll
  for (int cs = 0; cs < 8; ++cs) {
    int kk = cs * 2 + h;
    s8v a0 = Wv[o0 * 16 + (kk ^ (o0 & 7))];
    s8v a1 = Wv[o1 * 16 + (kk ^ (o1 & 7))];
    s8v b0 = Xv[kk * 128 + wsp + l31];
    s8v b1 = Xv[kk * 128 + wsp + 32 + l31];
    acc00 = __builtin_amdgcn_mfma_f32_32x32x16_bf16(a0, b0, acc00, 0, 0, 0);
    acc01 = __builtin_amdgcn_mfma_f32_32x32x16_bf16(a0, b1, acc01, 0, 0, 0);
    acc10 = __builtin_amdgcn_mfma_f32_32x32x16_bf16(a1, b0, acc10, 0, 0, 0);
    acc11 = __builtin_amdgcn_mfma_f32_32x32x16_bf16(a1, b1, acc11, 0, 0, 0);
  }
  // transpose via LDS -> coalesced head-layout u16 stores
  __syncthreads();
  unsigned short* ot = smem; // [128][132]
  #pragma unroll
  for (int reg = 0; reg < 16; ++reg) {
    int rm = (reg & 3) + ((reg >> 2) << 3) + (h << 2);
    ot[(wo + rm) * 132 + wsp + l31]           = f2bf(acc00[reg] * outScale);
    ot[(wo + rm) * 132 + wsp + 32 + l31]      = f2bf(acc01[reg] * outScale);
    ot[(wo + 32 + rm) * 132 + wsp + l31]      = f2bf(acc10[reg] * outScale);
    ot[(wo + 32 + rm) * 132 + wsp + 32 + l31] = f2bf(acc11[reg] * outScale);
  }
  __syncthreads();
  int d = t & 31;
  for (int i = 0; i < 64; ++i) {
    int idx2 = (t >> 5) + (i << 3);
    int s = idx2 & 127, ohi = idx2 >> 7;
    po[((size_t)(n * 4 + ohi) * S + s0 + s) * 32 + d] = ot[(ohi * 32 + d) * 132 + s];
  }
}

// ------------- final conv1x1 (hi/lo split bf16, 3 MFMAs) -> f32 NCS out -------------
// grid = N * (S/64) * 2 (o-half per block). TS=64.
__global__ __launch_bounds__(256) void conv_hilo_k(
    const float* __restrict__ x, const float* __restrict__ W,
    const float* __restrict__ bias, float* __restrict__ out, int S)
{
  __shared__ __align__(16) unsigned short smem[32768]; // 64KB
  unsigned short* Whi = smem;
  unsigned short* Wlo = smem + 8192;
  unsigned short* Xhi = smem + 16384;
  unsigned short* Xlo = smem + 24576;
  int t = threadIdx.x;
  int spb = S >> 6;
  int bid = blockIdx.x;
  int oh_ = bid & 1;
  int sb  = (bid >> 1) % spb;
  int n   = (bid >> 1) / spb;
  int s0  = sb << 6;

  #pragma unroll
  for (int k = 0; k < 8; ++k) {
    int f4 = t + (k << 8);
    int o = f4 >> 5, cq = f4 & 31; // o-local 0..63
    float4 wq = *(const float4*)(W + (size_t)(oh_ * 64 + o) * 128 + cq * 4);
    float vv[4] = {wq.x, wq.y, wq.z, wq.w};
    s4v hv, lv;
    #pragma unroll
    for (int e = 0; e < 4; ++e) {
      unsigned short hb = f2bf(vv[e]);
      hv[e] = (short)hb;
      lv[e] = (short)f2bf(vv[e] - __uint_as_float((unsigned)hb << 16));
    }
    int blkw = (o * 16 + ((cq >> 1) ^ (o & 7))) * 8 + (cq & 1) * 4;
    *(s4v*)(Whi + blkw) = hv;
    *(s4v*)(Wlo + blkw) = lv;
  }
  int sl = t & 63, coh = t >> 6;
  for (int co = coh; co < 16; co += 4) {
    const float* xb = x + (size_t)(n * 128 + co * 8) * S + s0 + sl;
    union { unsigned short u[8]; s8v v; } hx, lx;
    #pragma unroll
    for (int e = 0; e < 8; ++e) {
      float vv = xb[(size_t)e * S];
      unsigned short hb = f2bf(vv);
      hx.u[e] = hb;
      lx.u[e] = f2bf(vv - __uint_as_float((unsigned)hb << 16));
    }
    *(s8v*)(Xhi + (co * 64 + sl) * 8) = hx.v;
    *(s8v*)(Xlo + (co * 64 + sl) * 8) = lx.v;
  }
  __syncthreads();

  int lane = t & 63, w = t >> 6;
  int l31 = lane & 31, h = lane >> 5;
  int ol  = ((w & 1) << 5) + l31; // o-local
  int s_l = ((w >> 1) << 5) + l31;
  f16v acc = {};
  #pragma unroll
  for (int reg = 0; reg < 16; ++reg) {
    int rm = (reg & 3) + ((reg >> 2) << 3) + (h << 2);
    acc[reg] = bias[oh_ * 64 + ((w & 1) << 5) + rm];
  }
  const s8v* WHv = (const s8v*)Whi;
  const s8v* WLv = (const s8v*)Wlo;
  const s8v* XHv = (const s8v*)Xhi;
  const s8v* XLv = (const s8v*)Xlo;
  #pragma unroll
  for (int cs = 0; cs < 8; ++cs) {
    int kk = cs * 2 + h;
    int ia = ol * 16 + (kk ^ (ol & 7));
    int ib = kk * 64 + s_l;
    s8v ah = WHv[ia], al = WLv[ia];
    s8v bh = XHv[ib], bl = XLv[ib];
    acc = __builtin_amdgcn_mfma_f32_32x32x16_bf16(ah, bh, acc, 0, 0, 0);
    acc = __builtin_amdgcn_mfma_f32_32x32x16_bf16(ah, bl, acc, 0, 0, 0);
    acc = __builtin_amdgcn_mfma_f32_32x32x16_bf16(al, bh, acc, 0, 0, 0);
  }
  #pragma unroll
  for (int reg = 0; reg < 16; ++reg) {
    int rm = (reg & 3) + ((reg >> 2) << 3) + (h << 2);
    out[(size_t)(n * 128 + oh_ * 64 + ((w & 1) << 5) + rm) * S + s0 + s_l] = acc[reg];
  }
}

// ------------- fused attention: 1 block = (n,h) x 128 q-rows, 4 waves x 32 rows -------------
// qh/kh/vh: [N*4][L][32] bf16 (q pre-scaled). oh: [N][128][4096] f32.
__global__ __launch_bounds__(256) void attn_k(
    const unsigned short* __restrict__ qh, const unsigned short* __restrict__ kh,
    const unsigned short* __restrict__ vh, float* __restrict__ oh)
{
  __shared__ __align__(16) unsigned short Qsw[4096];
  __shared__ __align__(16) unsigned short Ksw[1024];
  __shared__ __align__(16) unsigned short Vsw[1024];
  __shared__ __align__(16) float otf[128 * 33];
  __shared__ float l_arr[128];
  int t = threadIdx.x;
  int lane = t & 63, w = t >> 6;
  int l31 = lane & 31, h = lane >> 5;
  int blk = blockIdx.x;
  int nh = blk & 31, qb = blk >> 5;
  size_t qbase = ((size_t)nh * 4096 + (size_t)qb * 128) * 32;

  // stage Q (frag-major: block = (w*4 + dh*2 + hh)*32 + r, elem = d&7)
  #pragma unroll
  for (int k = 0; k < 4; ++k) {
    int fq = t + (k << 8);
    int rl = fq >> 3, qd = fq & 7;
    s4v qv = *(const s4v*)(qh + qbase + (size_t)rl * 32 + qd * 4);
    int blkq = ((rl >> 5) * 4 + (qd >> 2) * 2 + ((qd >> 1) & 1)) * 32 + (rl & 31);
    *(s4v*)(Qsw + blkq * 8 + (qd & 1) * 4) = qv;
  }
  __syncthreads();
  const s8v* Qv = (const s8v*)Qsw;
  s8v qf0 = Qv[(w * 4 + h) * 32 + l31];
  s8v qf1 = Qv[(w * 4 + 2 + h) * 32 + l31];
  const s8v* Kv = (const s8v*)Ksw;
  const s8v* Vv = (const s8v*)Vsw;
  f16v oacc = {};
  float l_part = 0.f;
  size_t kvbase = (size_t)nh * 1024 * 32;

  for (int tile = 0; tile < 32; ++tile) {
    int j0 = tile << 5;
    __syncthreads();
    if (t < 128) {
      int j = t & 31, dq = t >> 5;
      s8v kv = *(const s8v*)(kh + kvbase + (size_t)(j0 + j) * 32 + dq * 8);
      *(s8v*)(Ksw + (dq * 32 + j) * 8) = kv;
    } else {
      int tt = t - 128;
      int dv = tt & 31, oc = tt >> 5;
      union { unsigned short u[8]; s8v v; } tv;
      #pragma unroll
      for (int e = 0; e < 8; ++e)
        tv.u[e] = vh[kvbase + (size_t)(j0 + oc * 8 + e) * 32 + dv];
      *(s8v*)(Vsw + (oc * 32 + dv) * 8) = tv.v;
    }
    __syncthreads();
    // swapped QK^T: S[j][r] — lane owns q-row r=l31, j's = (reg&3)+8*(reg>>2)+4h
    s8v kf0 = Kv[h * 32 + l31];
    s8v kf1 = Kv[(2 + h) * 32 + l31];
    f16v sf = {};
    sf = __builtin_amdgcn_mfma_f32_32x32x16_bf16(kf0, qf0, sf, 0, 0, 0);
    sf = __builtin_amdgcn_mfma_f32_32x32x16_bf16(kf1, qf1, sf, 0, 0, 0);
    float p[16];
    #pragma unroll
    for (int r = 0; r < 16; ++r) { p[r] = exp2f(sf[r] * LOG2E); l_part += p[r]; }
    unsigned pk[8], pp[8];
    #pragma unroll
    for (int q = 0; q < 8; ++q) {
      pk[q] = pack2bf(p[2 * q], p[2 * q + 1]);
      pp[q] = (unsigned)__shfl_xor((int)pk[q], 32);
    }
    // assemble P A-frags (j = 16c + 8h + e), partner half via shfl_xor(32)
    union { unsigned u[4]; s8v v; } u0, u1;
    u0.u[0] = h ? pp[2] : pk[0];
    u0.u[1] = h ? pp[3] : pk[1];
    u0.u[2] = h ? pk[2] : pp[0];
    u0.u[3] = h ? pk[3] : pp[1];
    u1.u[0] = h ? pp[6] : pk[4];
    u1.u[1] = h ? pp[7] : pk[5];
    u1.u[2] = h ? pk[6] : pp[4];
    u1.u[3] = h ? pk[7] : pp[5];
    s8v vf0 = Vv[h * 32 + l31];
    s8v vf1 = Vv[(2 + h) * 32 + l31];
    oacc = __builtin_amdgcn_mfma_f32_32x32x16_bf16(u0.v, vf0, oacc, 0, 0, 0);
    oacc = __builtin_amdgcn_mfma_f32_32x32x16_bf16(u1.v, vf1, oacc, 0, 0, 0);
  }
  float l_tot = l_part + __shfl_xor(l_part, 32);
  l_arr[w * 32 + l31] = l_tot;
  __syncthreads();
  #pragma unroll
  for (int reg = 0; reg < 16; ++reg) {
    int rm = (reg & 3) + ((reg >> 2) << 3) + (h << 2);
    otf[(w * 32 + rm) * 33 + l31] = oacc[reg];
  }
  __syncthreads();
  int n = nh >> 2, hh = nh & 3;
  for (int i = 0; i < 16; ++i) {
    int flat = t + (i << 8);
    int r = flat & 127, dv = flat >> 7;
    float val = otf[r * 33 + dv] / l_arr[r];
    oh[(size_t)(n * 128 + hh * 32 + dv) * 4096 + qb * 128 + r] = val;
  }
}

extern "C" void kernel_launch(void* const* d_in, const int* in_sizes, int n_in,
                              void* d_out, int out_size, void* d_ws, size_t ws_size,
                              hipStream_t stream)
{
  (void)in_sizes; (void)n_in; (void)out_size; (void)ws_size;
  const float* q_src = (const float*)d_in[0];
  const float* k_src = (const float*)d_in[1];
  const float* v_src = (const float*)d_in[2];
  const float* Wq = (const float*)d_in[3];
  const float* bq = (const float*)d_in[4];
  const float* Wk = (const float*)d_in[5];
  const float* bk = (const float*)d_in[6];
  const float* Wv = (const float*)d_in[7];
  const float* bv = (const float*)d_in[8];
  const float* Wp = (const float*)d_in[9];
  const float* bp = (const float*)d_in[10];
  const float* g_nq  = (const float*)d_in[11];
  const float* b_nq  = (const float*)d_in[12];
  const float* g_nk  = (const float*)d_in[13];
  const float* b_nk  = (const float*)d_in[14];
  const float* g_nv  = (const float*)d_in[15];
  const float* b_nv  = (const float*)d_in[16];
  const float* g_srk = (const float*)d_in[17];
  const float* b_srk = (const float*)d_in[18];
  const float* g_srv = (const float*)d_in[19];
  const float* b_srv = (const float*)d_in[20];

  float* ws = (float*)d_ws;
  float* qn  = ws;                 // 4,194,304 f32 (reused as attention output)
  float* ohb = ws;
  unsigned short* qhb = (unsigned short*)(ws + 4194304); // 4,194,304 u16
  unsigned short* khb = qhb + 4194304;                   // 1,048,576 u16
  unsigned short* vhb = khb + 1048576;                   // 1,048,576 u16
  float* knp = (float*)(vhb + 1048576);                  // 1,048,576 f32
  float* vnp = knp + 1048576;                            // 1,048,576 f32

  const float SCALE = 0.17677669529663688f; // (128/4)^-0.5

  gn_apply_k<<<256, 256, 0, stream>>>(q_src, g_nq, b_nq, qn);
  pool_gn2_k<<<256, 256, 0, stream>>>(k_src, g_srk, b_srk, g_nk, b_nk, knp);
  pool_gn2_k<<<256, 256, 0, stream>>>(v_src, g_srv, b_srv, g_nv, b_nv, vnp);
  conv1x1_k<<<256, 256, 0, stream>>>(qn,  Wq, bq, qhb, 4096, SCALE);
  conv1x1_k<<<64,  256, 0, stream>>>(knp, Wk, bk, khb, 1024, 1.0f);
  conv1x1_k<<<64,  256, 0, stream>>>(vnp, Wv, bv, vhb, 1024, 1.0f);
  attn_k<<<1024, 256, 0, stream>>>(qhb, khb, vhb, ohb);
  conv_hilo_k<<<1024, 256, 0, stream>>>(ohb, Wp, bp, (float*)d_out, 4096);
}

// Round 2
// 118.621 us; speedup vs baseline: 1.2811x; 1.2811x over previous
//
#include <hip/hip_runtime.h>

#define LOG2E 1.44269504088896340f

typedef __attribute__((ext_vector_type(8)))  short s8v;
typedef __attribute__((ext_vector_type(4)))  short s4v;
typedef __attribute__((ext_vector_type(16))) float f16v;
typedef __attribute__((ext_vector_type(2)))  int   i2v;

__device__ __forceinline__ unsigned short f2bf(float f) {
  union { float f; unsigned u; } v; v.f = f;
  unsigned r = v.u + 0x7FFFu + ((v.u >> 16) & 1u);
  return (unsigned short)(r >> 16);
}
__device__ __forceinline__ float bf2f(unsigned short b) {
  return __uint_as_float((unsigned)b << 16);
}

// ---------------- GN stats (q path): per (n,g) -> per-channel affine ----------------
__global__ __launch_bounds__(256) void gn_stats_k(
    const float* __restrict__ x, const float* __restrict__ gamma,
    const float* __restrict__ beta, float* __restrict__ ab)
{
  __shared__ float Sc[4], Qc[4];
  int blk = blockIdx.x; int n = blk >> 5, g = blk & 31;
  int t = threadIdx.x; int cl = t >> 6, lane = t & 63;
  const float4* x4 = (const float4*)(x + (size_t)(n * 128 + g * 4 + cl) * 4096);
  float s = 0.f, ss = 0.f;
  #pragma unroll
  for (int j = 0; j < 16; ++j) {
    float4 v = x4[lane + 64 * j];
    s  += v.x + v.y + v.z + v.w;
    ss += v.x * v.x + v.y * v.y + v.z * v.z + v.w * v.w;
  }
  #pragma unroll
  for (int m = 32; m >= 1; m >>= 1) { s += __shfl_xor(s, m); ss += __shfl_xor(ss, m); }
  if (lane == 0) { Sc[cl] = s; Qc[cl] = ss; }
  __syncthreads();
  if (t < 4) {
    float mu = (Sc[0] + Sc[1] + Sc[2] + Sc[3]) * (1.f / 16384.f);
    float e  = (Qc[0] + Qc[1] + Qc[2] + Qc[3]) * (1.f / 16384.f);
    float r  = rsqrtf(e - mu * mu + 1e-5f);
    int c = g * 4 + t;
    float al = gamma[c] * r;
    ab[n * 128 + c] = al;
    ab[1024 + n * 128 + c] = beta[c] - mu * al;
  }
}

// ------- avgpool2 + composed double-GN affine (k/v path): per (n,g) -------
__global__ __launch_bounds__(256) void pool_aff_k(
    const float* __restrict__ x,
    const float* __restrict__ g1, const float* __restrict__ b1,
    const float* __restrict__ g2, const float* __restrict__ b2,
    float* __restrict__ pooled, float* __restrict__ ab)
{
  __shared__ float Sc[4], Qc[4];
  int blk = blockIdx.x; int n = blk >> 5, g = blk & 31;
  int t = threadIdx.x; int cl = t >> 6, lane = t & 63;
  int c = g * 4 + cl;
  const float* xb = x + (size_t)(n * 128 + c) * 4096;
  float* pb = pooled + (size_t)(n * 128 + c) * 1024;
  float s = 0.f, ss = 0.f;
  #pragma unroll
  for (int j = 0; j < 16; ++j) {
    int p = lane + 64 * j;
    int py = p >> 5, px = p & 31;
    float2 a = ((const float2*)(xb + py * 128))[px];
    float2 b = ((const float2*)(xb + py * 128 + 64))[px];
    float v = 0.25f * (a.x + a.y + b.x + b.y);
    pb[p] = v; s += v; ss += v * v;
  }
  #pragma unroll
  for (int m = 32; m >= 1; m >>= 1) { s += __shfl_xor(s, m); ss += __shfl_xor(ss, m); }
  if (lane == 0) { Sc[cl] = s; Qc[cl] = ss; }
  __syncthreads();
  if (t < 4) {
    float mu1 = (Sc[0] + Sc[1] + Sc[2] + Sc[3]) * (1.f / 4096.f);
    float e1  = (Qc[0] + Qc[1] + Qc[2] + Qc[3]) * (1.f / 4096.f);
    float r1  = rsqrtf(e1 - mu1 * mu1 + 1e-5f);
    float mzs = 0.f, e2s = 0.f;
    #pragma unroll
    for (int cc = 0; cc < 4; ++cc) {
      int ch = g * 4 + cc;
      float a = r1 * g1[ch];
      float d = b1[ch] - mu1 * a;
      float m = Sc[cc] * (1.f / 1024.f);
      float q = Qc[cc] * (1.f / 1024.f);
      mzs += a * m + d;
      e2s += a * a * q + 2.f * a * d * m + d * d;
    }
    float mu2 = 0.25f * mzs;
    float r2  = rsqrtf(0.25f * e2s - mu2 * mu2 + 1e-5f);
    int ch = g * 4 + t;
    float a = r1 * g1[ch];
    float d = b1[ch] - mu1 * a;
    ab[n * 128 + ch] = a * r2 * g2[ch];
    ab[1024 + n * 128 + ch] = (d - mu2) * r2 * g2[ch] + b2[ch];
  }
}

// ------- conv1x1 with fused input affine (bf16 MFMA) -> head-layout or V^T out -------
// x: [N][128][S] f32 raw.  head out: [N*4][S][32] u16.  V^T out: [N*4][32][S] u16.
__global__ __launch_bounds__(256) void conv_aff_k(
    const float* __restrict__ x, const float* __restrict__ ab,
    const float* __restrict__ W, const float* __restrict__ bias,
    unsigned short* __restrict__ po, int S, float outScale, int vt_mode)
{
  __shared__ __align__(16) unsigned short smem[32768]; // 64KB: Wsw 32K | xsw 32K; reused as ot
  unsigned short* Wsw = smem;
  unsigned short* xsw = smem + 16384;
  int t = threadIdx.x;
  int spb = S >> 7;
  int n  = blockIdx.x / spb;
  int s0 = (blockIdx.x % spb) << 7;

  // stage W (bf16, 16B-block swizzled: block = o*16 + ((c>>3) ^ (o&7)))
  #pragma unroll
  for (int k = 0; k < 16; ++k) {
    int f4 = t + (k << 8);
    int o = f4 >> 5, cq = f4 & 31;
    float4 wq = *(const float4*)(W + (size_t)o * 128 + cq * 4);
    s4v hv;
    hv[0] = (short)f2bf(wq.x); hv[1] = (short)f2bf(wq.y);
    hv[2] = (short)f2bf(wq.z); hv[3] = (short)f2bf(wq.w);
    *(s4v*)(Wsw + (o * 16 + ((cq >> 1) ^ (o & 7))) * 8 + (cq & 1) * 4) = hv;
  }
  // stage x with affine (bf16, frag-major: block = (c>>3)*128 + s, elem = c&7)
  int sl = t & 127, coh = t >> 7;
  for (int co = coh; co < 16; co += 2) {
    const float* xb = x + (size_t)(n * 128 + co * 8) * S + s0 + sl;
    const float* aa = ab + n * 128 + co * 8;
    const float* bb = aa + 1024;
    union { unsigned short u[8]; s8v v; } xv;
    #pragma unroll
    for (int e = 0; e < 8; ++e) xv.u[e] = f2bf(fmaf(xb[(size_t)e * S], aa[e], bb[e]));
    *(s8v*)(xsw + (co * 128 + sl) * 8) = xv.v;
  }
  __syncthreads();

  int lane = t & 63, w = t >> 6;
  int l31 = lane & 31, h = lane >> 5;
  int wo = (w & 1) << 6, wsp = (w >> 1) << 6;
  f16v acc00 = {}, acc01 = {}, acc10 = {}, acc11 = {};
  #pragma unroll
  for (int reg = 0; reg < 16; ++reg) {
    int rm = (reg & 3) + ((reg >> 2) << 3) + (h << 2);
    float b0 = bias[wo + rm], b1 = bias[wo + 32 + rm];
    acc00[reg] = b0; acc01[reg] = b0; acc10[reg] = b1; acc11[reg] = b1;
  }
  const s8v* Wv = (const s8v*)Wsw;
  const s8v* Xv = (const s8v*)xsw;
  int o0 = wo + l31, o1 = wo + 32 + l31;
  #pragma unroll
  for (int cs = 0; cs < 8; ++cs) {
    int kk = cs * 2 + h;
    s8v a0 = Wv[o0 * 16 + (kk ^ (o0 & 7))];
    s8v a1 = Wv[o1 * 16 + (kk ^ (o1 & 7))];
    s8v b0 = Xv[kk * 128 + wsp + l31];
    s8v b1 = Xv[kk * 128 + wsp + 32 + l31];
    acc00 = __builtin_amdgcn_mfma_f32_32x32x16_bf16(a0, b0, acc00, 0, 0, 0);
    acc01 = __builtin_amdgcn_mfma_f32_32x32x16_bf16(a0, b1, acc01, 0, 0, 0);
    acc10 = __builtin_amdgcn_mfma_f32_32x32x16_bf16(a1, b0, acc10, 0, 0, 0);
    acc11 = __builtin_amdgcn_mfma_f32_32x32x16_bf16(a1, b1, acc11, 0, 0, 0);
  }
  // transpose via LDS -> coalesced u16 stores
  __syncthreads();
  unsigned short* ot = smem; // [128][132]
  #pragma unroll
  for (int reg = 0; reg < 16; ++reg) {
    int rm = (reg & 3) + ((reg >> 2) << 3) + (h << 2);
    ot[(wo + rm) * 132 + wsp + l31]           = f2bf(acc00[reg] * outScale);
    ot[(wo + rm) * 132 + wsp + 32 + l31]      = f2bf(acc01[reg] * outScale);
    ot[(wo + 32 + rm) * 132 + wsp + l31]      = f2bf(acc10[reg] * outScale);
    ot[(wo + 32 + rm) * 132 + wsp + 32 + l31] = f2bf(acc11[reg] * outScale);
  }
  __syncthreads();
  if (!vt_mode) {
    int d = t & 31;
    for (int i = 0; i < 64; ++i) {
      int idx2 = (t >> 5) + (i << 3);
      int s = idx2 & 127, ohi_ = idx2 >> 7;
      po[((size_t)(n * 4 + ohi_) * S + s0 + s) * 32 + d] = ot[(ohi_ * 32 + d) * 132 + s];
    }
  } else {
    int s = t & 127;
    for (int i = 0; i < 64; ++i) {
      int rr = (t >> 7) + i * 2;   // 0..127 = ohi*32 + d
      po[((size_t)(n * 4 + (rr >> 5)) * 32 + (rr & 31)) * S + s0 + s] = ot[rr * 132 + s];
    }
  }
}

// ------------- Wp hi/lo pre-split into conv-LDS image layout -------------
__global__ __launch_bounds__(256) void wsplit_k(
    const float* __restrict__ W, unsigned short* __restrict__ whi,
    unsigned short* __restrict__ wlo)
{
  int idx = blockIdx.x * 256 + threadIdx.x;
  #pragma unroll
  for (int k = 0; k < 4; ++k) {
    int f = idx + k * 4096;       // 0..16383
    int o = f >> 7, c = f & 127;
    float v = W[f];
    unsigned short hb = f2bf(v);
    unsigned short lb = f2bf(v - bf2f(hb));
    int cq = c >> 2;
    int adr = (o * 16 + ((cq >> 1) ^ (o & 7))) * 8 + (cq & 1) * 4 + (c & 3);
    whi[adr] = hb; wlo[adr] = lb;
  }
}

// ------------- final conv1x1 (hi/lo bf16, 3 MFMAs) -> f32 NCS out -------------
// xhi/xlo: [N][4096][128] u16. whi/wlo: pre-split image. grid = N*(S/64)*2.
__global__ __launch_bounds__(256) void conv_hilo_k(
    const unsigned short* __restrict__ xhi, const unsigned short* __restrict__ xlo,
    const unsigned short* __restrict__ whi, const unsigned short* __restrict__ wlo,
    const float* __restrict__ bias, float* __restrict__ out, int S)
{
  __shared__ __align__(16) unsigned short smem[32768]; // 64KB
  unsigned short* Whi = smem;
  unsigned short* Wlo = smem + 8192;
  unsigned short* Xhi = smem + 16384;
  unsigned short* Xlo = smem + 24576;
  int t = threadIdx.x;
  int spb = S >> 6;
  int bid = blockIdx.x;
  int oh_ = bid & 1;
  int sb  = (bid >> 1) % spb;
  int n   = (bid >> 1) / spb;
  int s0  = sb << 6;

  // W: straight vector copy of pre-split image
  #pragma unroll
  for (int i = 0; i < 4; ++i) {
    int u = t + i * 256;
    ((s8v*)Whi)[u] = ((const s8v*)(whi + oh_ * 8192))[u];
    ((s8v*)Wlo)[u] = ((const s8v*)(wlo + oh_ * 8192))[u];
  }
  // X: vector loads, XOR-swizzled LDS (key = c-oct & 7)
  #pragma unroll
  for (int i = 0; i < 4; ++i) {
    int co = t & 15, slx = (t >> 4) + i * 16;
    size_t g = ((size_t)n * 4096 + s0 + slx) * 128 + co * 8;
    int dst = ((co * 64 + slx) * 8) ^ ((co & 7) << 3);
    *(s8v*)(Xhi + dst) = *(const s8v*)(xhi + g);
    *(s8v*)(Xlo + dst) = *(const s8v*)(xlo + g);
  }
  __syncthreads();

  int lane = t & 63, w = t >> 6;
  int l31 = lane & 31, h = lane >> 5;
  int ol  = ((w & 1) << 5) + l31;
  int s_l = ((w >> 1) << 5) + l31;
  f16v acc = {};
  #pragma unroll
  for (int reg = 0; reg < 16; ++reg) {
    int rm = (reg & 3) + ((reg >> 2) << 3) + (h << 2);
    acc[reg] = bias[oh_ * 64 + ((w & 1) << 5) + rm];
  }
  const s8v* WHv = (const s8v*)Whi;
  const s8v* WLv = (const s8v*)Wlo;
  #pragma unroll
  for (int cs = 0; cs < 8; ++cs) {
    int kk = cs * 2 + h;
    int ia = ol * 16 + (kk ^ (ol & 7));
    int ix = ((kk * 64 + s_l) * 8) ^ ((kk & 7) << 3);
    s8v ah = WHv[ia], al = WLv[ia];
    s8v bh = *(const s8v*)(Xhi + ix);
    s8v bl = *(const s8v*)(Xlo + ix);
    acc = __builtin_amdgcn_mfma_f32_32x32x16_bf16(ah, bh, acc, 0, 0, 0);
    acc = __builtin_amdgcn_mfma_f32_32x32x16_bf16(ah, bl, acc, 0, 0, 0);
    acc = __builtin_amdgcn_mfma_f32_32x32x16_bf16(al, bh, acc, 0, 0, 0);
  }
  #pragma unroll
  for (int reg = 0; reg < 16; ++reg) {
    int rm = (reg & 3) + ((reg >> 2) << 3) + (h << 2);
    out[(size_t)(n * 128 + oh_ * 64 + ((w & 1) << 5) + rm) * S + s0 + s_l] = acc[reg];
  }
}

// ------------- fused attention: 1 block = (n,h) x 128 q-rows, KVBLK=64 -------------
// qh: [N*4][4096][32] bf16 (pre-scaled by SCALE*LOG2E). kh: [N*4][1024][32].
// vt: [N*4][32][1024].  out: hi/lo bf16 [N][4096][128].
__global__ __launch_bounds__(256) void attn_k(
    const unsigned short* __restrict__ qh, const unsigned short* __restrict__ kh,
    const unsigned short* __restrict__ vt, unsigned short* __restrict__ ohi,
    unsigned short* __restrict__ olo)
{
  __shared__ __align__(16) unsigned short Qsw[4096];
  __shared__ __align__(16) unsigned short Ksw[2048];
  __shared__ __align__(16) unsigned short Vsw[2048];
  __shared__ __align__(16) float otf[128 * 33];
  __shared__ float l_arr[128];
  int t = threadIdx.x;
  int lane = t & 63, w = t >> 6;
  int l31 = lane & 31, h = lane >> 5;
  int blk = blockIdx.x;
  int nh = blk & 31, qb = blk >> 5;
  size_t qbase = ((size_t)nh * 4096 + (size_t)qb * 128) * 32;

  // stage Q (frag-major: block = (w*4 + dh*2 + hh)*32 + r, elem = d&7)
  #pragma unroll
  for (int k = 0; k < 4; ++k) {
    int fq = t + (k << 8);
    int rl = fq >> 3, qd = fq & 7;
    s4v qv = *(const s4v*)(qh + qbase + (size_t)rl * 32 + qd * 4);
    int blkq = ((rl >> 5) * 4 + (qd >> 2) * 2 + ((qd >> 1) & 1)) * 32 + (rl & 31);
    *(s4v*)(Qsw + blkq * 8 + (qd & 1) * 4) = qv;
  }
  __syncthreads();
  const s8v* Qv = (const s8v*)Qsw;
  s8v qf0 = Qv[(w * 4 + h) * 32 + l31];
  s8v qf1 = Qv[(w * 4 + 2 + h) * 32 + l31];

  f16v oacc = {};
  float l_part = 0.f;
  size_t kvb = (size_t)nh * 32768;
  // K staging map: lanes 0-3 = c-octs (contiguous 64B), rows t>>2
  int k_oct = t & 3, k_row = t >> 2;
  int kb = ((k_row >> 5) * 4 + k_oct) * 32 + (k_row & 31);
  int k_dst = (kb * 8) ^ ((((kb >> 5) & 7)) << 3);
  const unsigned short* kg = kh + kvb + (size_t)k_row * 32 + k_oct * 8;
  // V staging map: lanes 0-7 = kv-octs (contiguous 128B), d-rows t>>3
  int v_oc = t & 7, v_dv = t >> 3;
  int v_dst = ((v_oc * 32 + v_dv) * 8) ^ ((v_oc & 7) << 3);
  const unsigned short* vg = vt + kvb + (size_t)v_dv * 1024 + v_oc * 8;

  for (int tile = 0; tile < 16; ++tile) {
    int j0 = tile << 6;
    *(s8v*)(Ksw + k_dst) = *(const s8v*)(kg + (size_t)j0 * 32);
    *(s8v*)(Vsw + v_dst) = *(const s8v*)(vg + j0);
    __syncthreads();
    #pragma unroll
    for (int s = 0; s < 2; ++s) {
      int o0 = s * 4 + h, o1 = s * 4 + 2 + h;
      int i0 = ((o0 * 32 + l31) * 8) ^ ((o0 & 7) << 3);
      int i1 = ((o1 * 32 + l31) * 8) ^ ((o1 & 7) << 3);
      s8v kf0 = *(const s8v*)(Ksw + i0);
      s8v kf1 = *(const s8v*)(Ksw + i1);
      f16v sf = {};
      sf = __builtin_amdgcn_mfma_f32_32x32x16_bf16(kf0, qf0, sf, 0, 0, 0);
      sf = __builtin_amdgcn_mfma_f32_32x32x16_bf16(kf1, qf1, sf, 0, 0, 0);
      float p[16];
      #pragma unroll
      for (int r = 0; r < 16; ++r) p[r] = exp2f(sf[r]);
      l_part += ((p[0] + p[1]) + (p[2] + p[3])) + ((p[4] + p[5]) + (p[6] + p[7]))
              + ((p[8] + p[9]) + (p[10] + p[11])) + ((p[12] + p[13]) + (p[14] + p[15]));
      unsigned c[8];
      #pragma unroll
      for (int q = 0; q < 8; ++q)
        asm("v_cvt_pk_bf16_f32 %0, %1, %2" : "=v"(c[q]) : "v"(p[2 * q]), "v"(p[2 * q + 1]));
      i2v s02 = __builtin_amdgcn_permlane32_swap((int)c[0], (int)c[2], false, false);
      i2v s13 = __builtin_amdgcn_permlane32_swap((int)c[1], (int)c[3], false, false);
      i2v s46 = __builtin_amdgcn_permlane32_swap((int)c[4], (int)c[6], false, false);
      i2v s57 = __builtin_amdgcn_permlane32_swap((int)c[5], (int)c[7], false, false);
      union { int u[4]; s8v v; } u0, u1;
      u0.u[0] = s02[0]; u0.u[1] = s13[0]; u0.u[2] = s02[1]; u0.u[3] = s13[1];
      u1.u[0] = s46[0]; u1.u[1] = s57[0]; u1.u[2] = s46[1]; u1.u[3] = s57[1];
      s8v vf0 = *(const s8v*)(Vsw + i0);
      s8v vf1 = *(const s8v*)(Vsw + i1);
      oacc = __builtin_amdgcn_mfma_f32_32x32x16_bf16(u0.v, vf0, oacc, 0, 0, 0);
      oacc = __builtin_amdgcn_mfma_f32_32x32x16_bf16(u1.v, vf1, oacc, 0, 0, 0);
    }
    __syncthreads();
  }
  float l_tot = l_part + __shfl_xor(l_part, 32);
  l_arr[w * 32 + l31] = 1.0f / l_tot;
  #pragma unroll
  for (int reg = 0; reg < 16; ++reg) {
    int rm = (reg & 3) + ((reg >> 2) << 3) + (h << 2);
    otf[(w * 32 + rm) * 33 + l31] = oacc[reg];
  }
  __syncthreads();
  int n = nh >> 2, hh = nh & 3;
  int dv = t & 31;
  for (int i = 0; i < 16; ++i) {
    int rr = (t >> 5) + (i << 3);
    float val = otf[rr * 33 + dv] * l_arr[rr];
    unsigned short hb = f2bf(val);
    unsigned short lb = f2bf(val - bf2f(hb));
    size_t adr = ((size_t)n * 4096 + (size_t)qb * 128 + rr) * 128 + hh * 32 + dv;
    ohi[adr] = hb; olo[adr] = lb;
  }
}

extern "C" void kernel_launch(void* const* d_in, const int* in_sizes, int n_in,
                              void* d_out, int out_size, void* d_ws, size_t ws_size,
                              hipStream_t stream)
{
  (void)in_sizes; (void)n_in; (void)out_size; (void)ws_size;
  const float* q_src = (const float*)d_in[0];
  const float* k_src = (const float*)d_in[1];
  const float* v_src = (const float*)d_in[2];
  const float* Wq = (const float*)d_in[3];
  const float* bq = (const float*)d_in[4];
  const float* Wk = (const float*)d_in[5];
  const float* bk = (const float*)d_in[6];
  const float* Wv = (const float*)d_in[7];
  const float* bv = (const float*)d_in[8];
  const float* Wp = (const float*)d_in[9];
  const float* bp = (const float*)d_in[10];
  const float* g_nq  = (const float*)d_in[11];
  const float* b_nq  = (const float*)d_in[12];
  const float* g_nk  = (const float*)d_in[13];
  const float* b_nk  = (const float*)d_in[14];
  const float* g_nv  = (const float*)d_in[15];
  const float* b_nv  = (const float*)d_in[16];
  const float* g_srk = (const float*)d_in[17];
  const float* b_srk = (const float*)d_in[18];
  const float* g_srv = (const float*)d_in[19];
  const float* b_srv = (const float*)d_in[20];

  unsigned short* qhb = (unsigned short*)d_ws;            // 8MB
  unsigned short* khb = qhb + 4194304;                    // 2MB
  unsigned short* vtb = khb + 1048576;                    // 2MB
  unsigned short* ohi = vtb + 1048576;                    // 8MB
  unsigned short* olo = ohi + 4194304;                    // 8MB
  float* knp = (float*)(olo + 4194304);                   // 4MB
  float* vnp = knp + 1048576;                             // 4MB
  float* qab = vnp + 1048576;                             // 8KB
  float* kab = qab + 2048;
  float* vab = kab + 2048;
  unsigned short* whi = (unsigned short*)(vab + 2048);    // 32KB
  unsigned short* wlo = whi + 16384;

  const float QSCALE = 0.17677669529663688f * LOG2E;      // (C/h)^-0.5 * log2(e)

  gn_stats_k<<<256, 256, 0, stream>>>(q_src, g_nq, b_nq, qab);
  pool_aff_k<<<256, 256, 0, stream>>>(k_src, g_srk, b_srk, g_nk, b_nk, knp, kab);
  pool_aff_k<<<256, 256, 0, stream>>>(v_src, g_srv, b_srv, g_nv, b_nv, vnp, vab);
  wsplit_k<<<16, 256, 0, stream>>>(Wp, whi, wlo);
  conv_aff_k<<<256, 256, 0, stream>>>(q_src, qab, Wq, bq, qhb, 4096, QSCALE, 0);
  conv_aff_k<<<64,  256, 0, stream>>>(knp, kab, Wk, bk, khb, 1024, 1.0f, 0);
  conv_aff_k<<<64,  256, 0, stream>>>(vnp, vab, Wv, bv, vtb, 1024, 1.0f, 1);
  attn_k<<<1024, 256, 0, stream>>>(qhb, khb, vtb, ohi, olo);
  conv_hilo_k<<<1024, 256, 0, stream>>>(ohi, olo, whi, wlo, bp, (float*)d_out, 4096);
}

// Round 4
// 70.680 us; speedup vs baseline: 2.1501x; 1.6783x over previous
//
#include <hip/hip_runtime.h>

typedef __attribute__((ext_vector_type(8)))  short s8v;
typedef __attribute__((ext_vector_type(4)))  short s4v;
typedef __attribute__((ext_vector_type(16))) float f16v;
typedef __attribute__((ext_vector_type(2)))  int   i2v;
typedef __attribute__((ext_vector_type(2)))  float f2v;

__device__ __forceinline__ unsigned short f2bf(float f) {
  union { float f; unsigned u; } v; v.f = f;
  unsigned r = v.u + 0x7FFFu + ((v.u >> 16) & 1u);
  return (unsigned short)(r >> 16);
}
__device__ __forceinline__ float bf2f(unsigned short b) {
  return __uint_as_float((unsigned)b << 16);
}
__device__ __forceinline__ float fexp2(float x) {
#if __has_builtin(__builtin_amdgcn_exp2f)
  return __builtin_amdgcn_exp2f(x);   // compiler-visible v_exp_f32: TRANS-use hazard handled
#else
  return exp2f(x);
#endif
}
__device__ __forceinline__ f2v mk2(float a, float b) { f2v r; r[0] = a; r[1] = b; return r; }

// ---------------- prep bodies ----------------
__device__ __forceinline__ void gn_stats_body(
    int blk, const float* __restrict__ x, const float* __restrict__ gamma,
    const float* __restrict__ beta, float* __restrict__ ab, float* sh)
{
  int n = blk >> 5, g = blk & 31;
  int t = threadIdx.x; int cl = t >> 6, lane = t & 63;
  const float4* x4 = (const float4*)(x + (size_t)(n * 128 + g * 4 + cl) * 4096);
  float s = 0.f, ss = 0.f;
  #pragma unroll
  for (int j = 0; j < 16; ++j) {
    float4 v = x4[lane + 64 * j];
    s  += v.x + v.y + v.z + v.w;
    ss += v.x * v.x + v.y * v.y + v.z * v.z + v.w * v.w;
  }
  #pragma unroll
  for (int m = 32; m >= 1; m >>= 1) { s += __shfl_xor(s, m); ss += __shfl_xor(ss, m); }
  if (lane == 0) { sh[cl] = s; sh[4 + cl] = ss; }
  __syncthreads();
  if (t < 4) {
    float mu = (sh[0] + sh[1] + sh[2] + sh[3]) * (1.f / 16384.f);
    float e  = (sh[4] + sh[5] + sh[6] + sh[7]) * (1.f / 16384.f);
    float r  = rsqrtf(e - mu * mu + 1e-5f);
    int c = g * 4 + t;
    float al = gamma[c] * r;
    ab[n * 128 + c] = al;
    ab[1024 + n * 128 + c] = beta[c] - mu * al;
  }
}

__device__ __forceinline__ void pool_aff_body(
    int blk, const float* __restrict__ x,
    const float* __restrict__ g1, const float* __restrict__ b1,
    const float* __restrict__ g2, const float* __restrict__ b2,
    float* __restrict__ pooled, float* __restrict__ ab, float* sh)
{
  int n = blk >> 5, g = blk & 31;
  int t = threadIdx.x; int cl = t >> 6, lane = t & 63;
  int c = g * 4 + cl;
  const float* xb = x + (size_t)(n * 128 + c) * 4096;
  float* pb = pooled + (size_t)(n * 128 + c) * 1024;
  float s = 0.f, ss = 0.f;
  #pragma unroll
  for (int j = 0; j < 16; ++j) {
    int p = lane + 64 * j;
    int py = p >> 5, px = p & 31;
    float2 a = ((const float2*)(xb + py * 128))[px];
    float2 b = ((const float2*)(xb + py * 128 + 64))[px];
    float v = 0.25f * (a.x + a.y + b.x + b.y);
    pb[p] = v; s += v; ss += v * v;
  }
  #pragma unroll
  for (int m = 32; m >= 1; m >>= 1) { s += __shfl_xor(s, m); ss += __shfl_xor(ss, m); }
  if (lane == 0) { sh[cl] = s; sh[4 + cl] = ss; }
  __syncthreads();
  if (t < 4) {
    float mu1 = (sh[0] + sh[1] + sh[2] + sh[3]) * (1.f / 4096.f);
    float e1  = (sh[4] + sh[5] + sh[6] + sh[7]) * (1.f / 4096.f);
    float r1  = rsqrtf(e1 - mu1 * mu1 + 1e-5f);
    float mzs = 0.f, e2s = 0.f;
    #pragma unroll
    for (int cc = 0; cc < 4; ++cc) {
      int ch = g * 4 + cc;
      float a = r1 * g1[ch];
      float d = b1[ch] - mu1 * a;
      float m = sh[cc] * (1.f / 1024.f);
      float q = sh[4 + cc] * (1.f / 1024.f);
      mzs += a * m + d;
      e2s += a * a * q + 2.f * a * d * m + d * d;
    }
    float mu2 = 0.25f * mzs;
    float r2  = rsqrtf(0.25f * e2s - mu2 * mu2 + 1e-5f);
    int ch = g * 4 + t;
    float a = r1 * g1[ch];
    float d = b1[ch] - mu1 * a;
    ab[n * 128 + ch] = a * r2 * g2[ch];
    ab[1024 + n * 128 + ch] = (d - mu2) * r2 * g2[ch] + b2[ch];
  }
}

__device__ __forceinline__ void wsplit_body(
    int b, const float* __restrict__ W, unsigned short* __restrict__ whi,
    unsigned short* __restrict__ wlo)
{
  int idx = b * 256 + threadIdx.x;
  #pragma unroll
  for (int k = 0; k < 4; ++k) {
    int f = idx + k * 4096;
    int o = f >> 7, c = f & 127;
    float v = W[f];
    unsigned short hb = f2bf(v);
    unsigned short lb = f2bf(v - bf2f(hb));
    int cq = c >> 2;
    int adr = (o * 16 + ((cq >> 1) ^ (o & 7))) * 8 + (cq & 1) * 4 + (c & 3);
    whi[adr] = hb; wlo[adr] = lb;
  }
}

__global__ __launch_bounds__(256) void prep_k(
    const float* __restrict__ q_src, const float* __restrict__ g_nq, const float* __restrict__ b_nq,
    const float* __restrict__ k_src, const float* __restrict__ g_srk, const float* __restrict__ b_srk,
    const float* __restrict__ g_nk, const float* __restrict__ b_nk,
    const float* __restrict__ v_src, const float* __restrict__ g_srv, const float* __restrict__ b_srv,
    const float* __restrict__ g_nv, const float* __restrict__ b_nv,
    const float* __restrict__ Wp,
    float* __restrict__ qab, float* __restrict__ kab, float* __restrict__ vab,
    float* __restrict__ knp, float* __restrict__ vnp,
    unsigned short* __restrict__ whi, unsigned short* __restrict__ wlo)
{
  __shared__ float sh[8];
  int b = blockIdx.x;
  if (b < 256) gn_stats_body(b, q_src, g_nq, b_nq, qab, sh);
  else if (b < 512) pool_aff_body(b - 256, k_src, g_srk, b_srk, g_nk, b_nk, knp, kab, sh);
  else if (b < 768) pool_aff_body(b - 512, v_src, g_srv, b_srv, g_nv, b_nv, vnp, vab, sh);
  else wsplit_body(b - 768, Wp, whi, wlo);
}

// ------- conv1x1 body with fused input affine (bf16 MFMA) -------
__device__ __forceinline__ void conv_body(
    int blk, const float* __restrict__ x, const float* __restrict__ ab,
    const float* __restrict__ W, const float* __restrict__ bias,
    unsigned short* __restrict__ po, int S, float outScale, int vt_mode,
    unsigned short* smem)
{
  unsigned short* Wsw = smem;
  unsigned short* xsw = smem + 16384;
  int t = threadIdx.x;
  int spb = S >> 7;
  int n  = blk / spb;
  int s0 = (blk % spb) << 7;

  #pragma unroll
  for (int k = 0; k < 16; ++k) {
    int f4 = t + (k << 8);
    int o = f4 >> 5, cq = f4 & 31;
    float4 wq = *(const float4*)(W + (size_t)o * 128 + cq * 4);
    s4v hv;
    hv[0] = (short)f2bf(wq.x); hv[1] = (short)f2bf(wq.y);
    hv[2] = (short)f2bf(wq.z); hv[3] = (short)f2bf(wq.w);
    *(s4v*)(Wsw + (o * 16 + ((cq >> 1) ^ (o & 7))) * 8 + (cq & 1) * 4) = hv;
  }
  int sl = t & 127, coh = t >> 7;
  for (int co = coh; co < 16; co += 2) {
    const float* xb = x + (size_t)(n * 128 + co * 8) * S + s0 + sl;
    const float* aa = ab + n * 128 + co * 8;
    const float* bb = aa + 1024;
    union { unsigned short u[8]; s8v v; } xv;
    #pragma unroll
    for (int e = 0; e < 8; ++e) xv.u[e] = f2bf(fmaf(xb[(size_t)e * S], aa[e], bb[e]));
    *(s8v*)(xsw + (co * 128 + sl) * 8) = xv.v;
  }
  __syncthreads();

  int lane = t & 63, w = t >> 6;
  int l31 = lane & 31, h = lane >> 5;
  int wo = (w & 1) << 6, wsp = (w >> 1) << 6;
  f16v acc00 = {}, acc01 = {}, acc10 = {}, acc11 = {};
  #pragma unroll
  for (int reg = 0; reg < 16; ++reg) {
    int rm = (reg & 3) + ((reg >> 2) << 3) + (h << 2);
    float b0 = bias[wo + rm], b1 = bias[wo + 32 + rm];
    acc00[reg] = b0; acc01[reg] = b0; acc10[reg] = b1; acc11[reg] = b1;
  }
  const s8v* Wv = (const s8v*)Wsw;
  const s8v* Xv = (const s8v*)xsw;
  int o0 = wo + l31, o1 = wo + 32 + l31;
  #pragma unroll
  for (int cs = 0; cs < 8; ++cs) {
    int kk = cs * 2 + h;
    s8v a0 = Wv[o0 * 16 + (kk ^ (o0 & 7))];
    s8v a1 = Wv[o1 * 16 + (kk ^ (o1 & 7))];
    s8v b0 = Xv[kk * 128 + wsp + l31];
    s8v b1 = Xv[kk * 128 + wsp + 32 + l31];
    acc00 = __builtin_amdgcn_mfma_f32_32x32x16_bf16(a0, b0, acc00, 0, 0, 0);
    acc01 = __builtin_amdgcn_mfma_f32_32x32x16_bf16(a0, b1, acc01, 0, 0, 0);
    acc10 = __builtin_amdgcn_mfma_f32_32x32x16_bf16(a1, b0, acc10, 0, 0, 0);
    acc11 = __builtin_amdgcn_mfma_f32_32x32x16_bf16(a1, b1, acc11, 0, 0, 0);
  }
  __syncthreads();
  unsigned short* ot = smem; // [128][132]
  #pragma unroll
  for (int reg = 0; reg < 16; ++reg) {
    int rm = (reg & 3) + ((reg >> 2) << 3) + (h << 2);
    ot[(wo + rm) * 132 + wsp + l31]           = f2bf(acc00[reg] * outScale);
    ot[(wo + rm) * 132 + wsp + 32 + l31]      = f2bf(acc01[reg] * outScale);
    ot[(wo + 32 + rm) * 132 + wsp + l31]      = f2bf(acc10[reg] * outScale);
    ot[(wo + 32 + rm) * 132 + wsp + 32 + l31] = f2bf(acc11[reg] * outScale);
  }
  __syncthreads();
  if (!vt_mode) {
    int d = t & 31;
    for (int i = 0; i < 64; ++i) {
      int idx2 = (t >> 5) + (i << 3);
      int s = idx2 & 127, ohi_ = idx2 >> 7;
      po[((size_t)(n * 4 + ohi_) * S + s0 + s) * 32 + d] = ot[(ohi_ * 32 + d) * 132 + s];
    }
  } else {
    int s = t & 127;
    for (int i = 0; i < 64; ++i) {
      int rr = (t >> 7) + i * 2;
      po[((size_t)(n * 4 + (rr >> 5)) * 32 + (rr & 31)) * S + s0 + s] = ot[rr * 132 + s];
    }
  }
}

__global__ __launch_bounds__(256) void convs_k(
    const float* __restrict__ q_src, const float* __restrict__ qab,
    const float* __restrict__ Wq, const float* __restrict__ bq, unsigned short* __restrict__ qhb,
    const float* __restrict__ knp, const float* __restrict__ kab,
    const float* __restrict__ Wk, const float* __restrict__ bk, unsigned short* __restrict__ khb,
    const float* __restrict__ vnp, const float* __restrict__ vab,
    const float* __restrict__ Wv, const float* __restrict__ bv, unsigned short* __restrict__ vtb,
    float qscale)
{
  __shared__ __align__(16) unsigned short smem[32768];
  int b = blockIdx.x;
  if (b < 256)      conv_body(b,       q_src, qab, Wq, bq, qhb, 4096, qscale, 0, smem);
  else if (b < 320) conv_body(b - 256, knp,   kab, Wk, bk, khb, 1024, 1.0f,   0, smem);
  else              conv_body(b - 320, vnp,   vab, Wv, bv, vtb, 1024, 1.0f,   1, smem);
}

// ------------- final conv1x1 (hi/lo bf16, 3 MFMAs) -> f32 NCS out -------------
__global__ __launch_bounds__(256) void conv_hilo_k(
    const unsigned short* __restrict__ xhi, const unsigned short* __restrict__ xlo,
    const unsigned short* __restrict__ whi, const unsigned short* __restrict__ wlo,
    const float* __restrict__ bias, float* __restrict__ out, int S)
{
  __shared__ __align__(16) unsigned short smem[32768];
  unsigned short* Whi = smem;
  unsigned short* Wlo = smem + 8192;
  unsigned short* Xhi = smem + 16384;
  unsigned short* Xlo = smem + 24576;
  int t = threadIdx.x;
  int spb = S >> 6;
  int bid = blockIdx.x;
  int oh_ = bid & 1;
  int sb  = (bid >> 1) % spb;
  int n   = (bid >> 1) / spb;
  int s0  = sb << 6;

  #pragma unroll
  for (int i = 0; i < 4; ++i) {
    int u = t + i * 256;
    ((s8v*)Whi)[u] = ((const s8v*)(whi + oh_ * 8192))[u];
    ((s8v*)Wlo)[u] = ((const s8v*)(wlo + oh_ * 8192))[u];
  }
  #pragma unroll
  for (int i = 0; i < 4; ++i) {
    int co = t & 15, slx = (t >> 4) + i * 16;
    size_t g = ((size_t)n * 4096 + s0 + slx) * 128 + co * 8;
    int dst = ((co * 64 + slx) * 8) ^ ((co & 7) << 3);
    *(s8v*)(Xhi + dst) = *(const s8v*)(xhi + g);
    *(s8v*)(Xlo + dst) = *(const s8v*)(xlo + g);
  }
  __syncthreads();

  int lane = t & 63, w = t >> 6;
  int l31 = lane & 31, h = lane >> 5;
  int ol  = ((w & 1) << 5) + l31;
  int s_l = ((w >> 1) << 5) + l31;
  f16v acc = {};
  #pragma unroll
  for (int reg = 0; reg < 16; ++reg) {
    int rm = (reg & 3) + ((reg >> 2) << 3) + (h << 2);
    acc[reg] = bias[oh_ * 64 + ((w & 1) << 5) + rm];
  }
  const s8v* WHv = (const s8v*)Whi;
  const s8v* WLv = (const s8v*)Wlo;
  #pragma unroll
  for (int cs = 0; cs < 8; ++cs) {
    int kk = cs * 2 + h;
    int ia = ol * 16 + (kk ^ (ol & 7));
    int ix = ((kk * 64 + s_l) * 8) ^ ((kk & 7) << 3);
    s8v ah = WHv[ia], al = WLv[ia];
    s8v bh = *(const s8v*)(Xhi + ix);
    s8v bl = *(const s8v*)(Xlo + ix);
    acc = __builtin_amdgcn_mfma_f32_32x32x16_bf16(ah, bh, acc, 0, 0, 0);
    acc = __builtin_amdgcn_mfma_f32_32x32x16_bf16(ah, bl, acc, 0, 0, 0);
    acc = __builtin_amdgcn_mfma_f32_32x32x16_bf16(al, bh, acc, 0, 0, 0);
  }
  #pragma unroll
  for (int reg = 0; reg < 16; ++reg) {
    int rm = (reg & 3) + ((reg >> 2) << 3) + (h << 2);
    out[(size_t)(n * 128 + oh_ * 64 + ((w & 1) << 5) + rm) * S + s0 + s_l] = acc[reg];
  }
}

// ------------- fused attention v3: dbuf + direct-Q + reg epilogue -------------
// qh: [N*4][4096][32] bf16 (pre-scaled by SCALE*log2e). kh: [N*4][1024][32].
// vt: [N*4][32][1024].  out: hi/lo bf16 [N][4096][128].
__global__ __launch_bounds__(256, 4) void attn_k(
    const unsigned short* __restrict__ qh, const unsigned short* __restrict__ kh,
    const unsigned short* __restrict__ vt, unsigned short* __restrict__ ohi,
    unsigned short* __restrict__ olo)
{
  __shared__ __align__(16) unsigned short Klds[2][2048];
  __shared__ __align__(16) unsigned short Vlds[2][2048];
  __shared__ float linv[128];
  int t = threadIdx.x;
  int lane = t & 63, w = t >> 6;
  int l31 = lane & 31, h = lane >> 5;
  int blk = blockIdx.x;
  int nh = blk & 31, qb = blk >> 5;

  // Q fragments straight from global (row = w*32+l31 of this q-block)
  const unsigned short* qp = qh + (((size_t)nh * 4096 + qb * 128 + w * 32 + l31) << 5);
  s8v qf0 = *(const s8v*)(qp + h * 8);
  s8v qf1 = *(const s8v*)(qp + (2 + h) * 8);

  size_t kvb = (size_t)nh << 15;
  // staging: thread t handles K global unit (row=t>>2, doct=t&3) -> coalesced
  const unsigned short* kg = kh + kvb + ((t >> 2) << 5) + ((t & 3) << 3);
  // V global unit (d=t>>3, koct=t&7) -> 128B contiguous per d-row
  const unsigned short* vg = vt + kvb + ((size_t)(t >> 3) << 10) + ((t & 7) << 3);
  // swizzled LDS dest units
  int ku = ((t >> 2) << 2) + ((t & 3) ^ ((t >> 3) & 3));
  int vu = ((t >> 3) << 3) + ((t & 7) ^ ((t >> 3) & 7));

  // prologue: stage tile 0 into buf 0
  s8v rk = *(const s8v*)kg;
  s8v rv = *(const s8v*)vg;
  *(s8v*)&Klds[0][ku * 8] = rk;
  *(s8v*)&Vlds[0][vu * 8] = rv;

  const f16v fz = {};
  f16v oacc = fz;
  f2v lp0 = mk2(0.f, 0.f), lp1 = mk2(0.f, 0.f);
  int kx = (l31 >> 1) & 3;
  int vx = l31 & 7;

  #pragma unroll 2
  for (int tile = 0; tile < 16; ++tile) {
    int buf = tile & 1;
    __syncthreads();              // buf's writes visible; prior reads of buf^1 done
    if (tile < 15) {              // issue next-tile loads AFTER barrier (stay in flight)
      int j0 = (tile + 1) << 6;
      rk = *(const s8v*)(kg + (size_t)j0 * 32);
      rv = *(const s8v*)(vg + j0);
    }
    const unsigned short* Kb = Klds[buf];
    const unsigned short* Vb = Vlds[buf];
    #pragma unroll
    for (int s = 0; s < 2; ++s) {
      int rb = s * 128 + l31 * 4;
      s8v kf0 = *(const s8v*)(Kb + ((rb + (h ^ kx)) << 3));
      s8v kf1 = *(const s8v*)(Kb + ((rb + ((2 + h) ^ kx)) << 3));
      f16v sf = __builtin_amdgcn_mfma_f32_32x32x16_bf16(kf0, qf0, fz, 0, 0, 0);
      sf = __builtin_amdgcn_mfma_f32_32x32x16_bf16(kf1, qf1, sf, 0, 0, 0);
      float p[16];
      #pragma unroll
      for (int r = 0; r < 16; ++r) p[r] = fexp2(sf[r]);
      lp0 += mk2(p[0], p[1]);  lp1 += mk2(p[2], p[3]);
      lp0 += mk2(p[4], p[5]);  lp1 += mk2(p[6], p[7]);
      lp0 += mk2(p[8], p[9]);  lp1 += mk2(p[10], p[11]);
      lp0 += mk2(p[12], p[13]); lp1 += mk2(p[14], p[15]);
      unsigned c[8];
      #pragma unroll
      for (int q = 0; q < 8; ++q)
        asm("v_cvt_pk_bf16_f32 %0, %1, %2" : "=v"(c[q]) : "v"(p[2 * q]), "v"(p[2 * q + 1]));
      i2v s02 = __builtin_amdgcn_permlane32_swap((int)c[0], (int)c[2], false, false);
      i2v s13 = __builtin_amdgcn_permlane32_swap((int)c[1], (int)c[3], false, false);
      i2v s46 = __builtin_amdgcn_permlane32_swap((int)c[4], (int)c[6], false, false);
      i2v s57 = __builtin_amdgcn_permlane32_swap((int)c[5], (int)c[7], false, false);
      union { int u[4]; s8v v; } u0, u1;
      u0.u[0] = s02[0]; u0.u[1] = s13[0]; u0.u[2] = s02[1]; u0.u[3] = s13[1];
      u1.u[0] = s46[0]; u1.u[1] = s57[0]; u1.u[2] = s46[1]; u1.u[3] = s57[1];
      s8v vf0 = *(const s8v*)(Vb + ((l31 * 8 + ((s * 4 + h) ^ vx)) << 3));
      s8v vf1 = *(const s8v*)(Vb + ((l31 * 8 + ((s * 4 + 2 + h) ^ vx)) << 3));
      oacc = __builtin_amdgcn_mfma_f32_32x32x16_bf16(u0.v, vf0, oacc, 0, 0, 0);
      oacc = __builtin_amdgcn_mfma_f32_32x32x16_bf16(u1.v, vf1, oacc, 0, 0, 0);
    }
    if (tile < 15) {              // write next tile into the other buffer
      *(s8v*)&Klds[buf ^ 1][ku * 8] = rk;
      *(s8v*)&Vlds[buf ^ 1][vu * 8] = rv;
    }
  }

  float l_part = lp0[0] + lp0[1] + lp1[0] + lp1[1];
  float l_tot = l_part + __shfl_xor(l_part, 32);
  if (h == 0) linv[w * 32 + l31] = 1.0f / l_tot;
  __syncthreads();
  int n = nh >> 2, hh = nh & 3;
  size_t obase = ((size_t)n * 4096 + qb * 128) * 128 + hh * 32 + l31;
  #pragma unroll
  for (int reg = 0; reg < 16; ++reg) {
    int rm = (reg & 3) + ((reg >> 2) << 3) + (h << 2);
    float val = oacc[reg] * linv[w * 32 + rm];
    unsigned short hb = f2bf(val);
    unsigned short lb = f2bf(val - bf2f(hb));
    size_t adr = obase + (size_t)(w * 32 + rm) * 128;
    ohi[adr] = hb; olo[adr] = lb;
  }
}

extern "C" void kernel_launch(void* const* d_in, const int* in_sizes, int n_in,
                              void* d_out, int out_size, void* d_ws, size_t ws_size,
                              hipStream_t stream)
{
  (void)in_sizes; (void)n_in; (void)out_size; (void)ws_size;
  const float* q_src = (const float*)d_in[0];
  const float* k_src = (const float*)d_in[1];
  const float* v_src = (const float*)d_in[2];
  const float* Wq = (const float*)d_in[3];
  const float* bq = (const float*)d_in[4];
  const float* Wk = (const float*)d_in[5];
  const float* bk = (const float*)d_in[6];
  const float* Wv = (const float*)d_in[7];
  const float* bv = (const float*)d_in[8];
  const float* Wp = (const float*)d_in[9];
  const float* bp = (const float*)d_in[10];
  const float* g_nq  = (const float*)d_in[11];
  const float* b_nq  = (const float*)d_in[12];
  const float* g_nk  = (const float*)d_in[13];
  const float* b_nk  = (const float*)d_in[14];
  const float* g_nv  = (const float*)d_in[15];
  const float* b_nv  = (const float*)d_in[16];
  const float* g_srk = (const float*)d_in[17];
  const float* b_srk = (const float*)d_in[18];
  const float* g_srv = (const float*)d_in[19];
  const float* b_srv = (const float*)d_in[20];

  unsigned short* qhb = (unsigned short*)d_ws;            // 8MB
  unsigned short* khb = qhb + 4194304;                    // 2MB
  unsigned short* vtb = khb + 1048576;                    // 2MB
  unsigned short* ohi = vtb + 1048576;                    // 8MB
  unsigned short* olo = ohi + 4194304;                    // 8MB
  float* knp = (float*)(olo + 4194304);                   // 4MB
  float* vnp = knp + 1048576;                             // 4MB
  float* qab = vnp + 1048576;                             // 8KB
  float* kab = qab + 2048;
  float* vab = kab + 2048;
  unsigned short* whi = (unsigned short*)(vab + 2048);    // 32KB
  unsigned short* wlo = whi + 16384;

  const float QSCALE = 0.17677669529663688f * 1.44269504088896340f;

  prep_k<<<784, 256, 0, stream>>>(q_src, g_nq, b_nq,
                                  k_src, g_srk, b_srk, g_nk, b_nk,
                                  v_src, g_srv, b_srv, g_nv, b_nv,
                                  Wp, qab, kab, vab, knp, vnp, whi, wlo);
  convs_k<<<384, 256, 0, stream>>>(q_src, qab, Wq, bq, qhb,
                                   knp, kab, Wk, bk, khb,
                                   vnp, vab, Wv, bv, vtb, QSCALE);
  attn_k<<<1024, 256, 0, stream>>>(qhb, khb, vtb, ohi, olo);
  conv_hilo_k<<<1024, 256, 0, stream>>>(ohi, olo, whi, wlo, bp, (float*)d_out, 4096);
}

// Round 6
// 70.415 us; speedup vs baseline: 2.1582x; 1.0038x over previous
//
#include <hip/hip_runtime.h>

typedef __attribute__((ext_vector_type(8)))  short s8v;
typedef __attribute__((ext_vector_type(4)))  short s4v;
typedef __attribute__((ext_vector_type(16))) float f16v;
typedef __attribute__((ext_vector_type(2)))  int   i2v;
typedef __attribute__((ext_vector_type(2)))  float f2v;

__device__ __forceinline__ unsigned short f2bf(float f) {
  union { float f; unsigned u; } v; v.f = f;
  unsigned r = v.u + 0x7FFFu + ((v.u >> 16) & 1u);
  return (unsigned short)(r >> 16);
}
__device__ __forceinline__ float bf2f(unsigned short b) {
  return __uint_as_float((unsigned)b << 16);
}
__device__ __forceinline__ float fexp2(float x) {
#if __has_builtin(__builtin_amdgcn_exp2f)
  return __builtin_amdgcn_exp2f(x);
#else
  return exp2f(x);
#endif
}
__device__ __forceinline__ f2v mk2(float a, float b) { f2v r; r[0] = a; r[1] = b; return r; }

// ---------------- prep bodies ----------------
__device__ __forceinline__ void gn_stats_body(
    int blk, const float* __restrict__ x, const float* __restrict__ gamma,
    const float* __restrict__ beta, float* __restrict__ ab, float* sh)
{
  int n = blk >> 5, g = blk & 31;
  int t = threadIdx.x; int cl = t >> 6, lane = t & 63;
  const float4* x4 = (const float4*)(x + (size_t)(n * 128 + g * 4 + cl) * 4096);
  float s = 0.f, ss = 0.f;
  #pragma unroll
  for (int j = 0; j < 16; ++j) {
    float4 v = x4[lane + 64 * j];
    s  += v.x + v.y + v.z + v.w;
    ss += v.x * v.x + v.y * v.y + v.z * v.z + v.w * v.w;
  }
  #pragma unroll
  for (int m = 32; m >= 1; m >>= 1) { s += __shfl_xor(s, m); ss += __shfl_xor(ss, m); }
  if (lane == 0) { sh[cl] = s; sh[4 + cl] = ss; }
  __syncthreads();
  if (t < 4) {
    float mu = (sh[0] + sh[1] + sh[2] + sh[3]) * (1.f / 16384.f);
    float e  = (sh[4] + sh[5] + sh[6] + sh[7]) * (1.f / 16384.f);
    float r  = rsqrtf(e - mu * mu + 1e-5f);
    int c = g * 4 + t;
    float al = gamma[c] * r;
    ab[n * 128 + c] = al;
    ab[1024 + n * 128 + c] = beta[c] - mu * al;
  }
}

__device__ __forceinline__ void pool_aff_body(
    int blk, const float* __restrict__ x,
    const float* __restrict__ g1, const float* __restrict__ b1,
    const float* __restrict__ g2, const float* __restrict__ b2,
    float* __restrict__ pooled, float* __restrict__ ab, float* sh)
{
  int n = blk >> 5, g = blk & 31;
  int t = threadIdx.x; int cl = t >> 6, lane = t & 63;
  int c = g * 4 + cl;
  const float* xb = x + (size_t)(n * 128 + c) * 4096;
  float* pb = pooled + (size_t)(n * 128 + c) * 1024;
  float s = 0.f, ss = 0.f;
  #pragma unroll
  for (int j = 0; j < 8; ++j) {
    int pp = (lane + 64 * j) * 2;      // even pooled index
    int py = pp >> 5, px2 = pp & 31;   // pooled row / col base (even)
    const float* r0 = xb + py * 128 + px2 * 2;   // unpooled row 2*py (stride 64), col 2*px2
    float4 A = *(const float4*)r0;
    float4 B = *(const float4*)(r0 + 64);        // unpooled row 2*py+1
    float v0 = 0.25f * (A.x + A.y + B.x + B.y);
    float v1 = 0.25f * (A.z + A.w + B.z + B.w);
    float2 wv; wv.x = v0; wv.y = v1;
    *(float2*)(pb + pp) = wv;
    s += v0 + v1; ss += v0 * v0 + v1 * v1;
  }
  #pragma unroll
  for (int m = 32; m >= 1; m >>= 1) { s += __shfl_xor(s, m); ss += __shfl_xor(ss, m); }
  if (lane == 0) { sh[cl] = s; sh[4 + cl] = ss; }
  __syncthreads();
  if (t < 4) {
    float mu1 = (sh[0] + sh[1] + sh[2] + sh[3]) * (1.f / 4096.f);
    float e1  = (sh[4] + sh[5] + sh[6] + sh[7]) * (1.f / 4096.f);
    float r1  = rsqrtf(e1 - mu1 * mu1 + 1e-5f);
    float mzs = 0.f, e2s = 0.f;
    #pragma unroll
    for (int cc = 0; cc < 4; ++cc) {
      int ch = g * 4 + cc;
      float a = r1 * g1[ch];
      float d = b1[ch] - mu1 * a;
      float m = sh[cc] * (1.f / 1024.f);
      float q = sh[4 + cc] * (1.f / 1024.f);
      mzs += a * m + d;
      e2s += a * a * q + 2.f * a * d * m + d * d;
    }
    float mu2 = 0.25f * mzs;
    float r2  = rsqrtf(0.25f * e2s - mu2 * mu2 + 1e-5f);
    int ch = g * 4 + t;
    float a = r1 * g1[ch];
    float d = b1[ch] - mu1 * a;
    ab[n * 128 + ch] = a * r2 * g2[ch];
    ab[1024 + n * 128 + ch] = (d - mu2) * r2 * g2[ch] + b2[ch];
  }
}

__device__ __forceinline__ void wsplit_body(
    int b, const float* __restrict__ W, unsigned short* __restrict__ whi,
    unsigned short* __restrict__ wlo)
{
  int idx = b * 256 + threadIdx.x;
  #pragma unroll
  for (int k = 0; k < 4; ++k) {
    int f = idx + k * 4096;
    int o = f >> 7, c = f & 127;
    float v = W[f];
    unsigned short hb = f2bf(v);
    unsigned short lb = f2bf(v - bf2f(hb));
    int cq = c >> 2;
    int adr = (o * 16 + ((cq >> 1) ^ (o & 7))) * 8 + (cq & 1) * 4 + (c & 3);
    whi[adr] = hb; wlo[adr] = lb;
  }
}

__global__ __launch_bounds__(256) void prep_k(
    const float* __restrict__ q_src, const float* __restrict__ g_nq, const float* __restrict__ b_nq,
    const float* __restrict__ k_src, const float* __restrict__ g_srk, const float* __restrict__ b_srk,
    const float* __restrict__ g_nk, const float* __restrict__ b_nk,
    const float* __restrict__ v_src, const float* __restrict__ g_srv, const float* __restrict__ b_srv,
    const float* __restrict__ g_nv, const float* __restrict__ b_nv,
    const float* __restrict__ Wp,
    float* __restrict__ qab, float* __restrict__ kab, float* __restrict__ vab,
    float* __restrict__ knp, float* __restrict__ vnp,
    unsigned short* __restrict__ whi, unsigned short* __restrict__ wlo)
{
  __shared__ float sh[8];
  int b = blockIdx.x;
  if (b < 256) gn_stats_body(b, q_src, g_nq, b_nq, qab, sh);
  else if (b < 512) pool_aff_body(b - 256, k_src, g_srk, b_srk, g_nk, b_nk, knp, kab, sh);
  else if (b < 768) pool_aff_body(b - 512, v_src, g_srv, b_srv, g_nv, b_nv, vnp, vab, sh);
  else wsplit_body(b - 768, Wp, whi, wlo);
}

// ------- conv1x1 body with fused input affine (bf16 MFMA) -------
__device__ __forceinline__ void conv_body(
    int blk, const float* __restrict__ x, const float* __restrict__ ab,
    const float* __restrict__ W, const float* __restrict__ bias,
    unsigned short* __restrict__ po, int S, float outScale, int vt_mode,
    unsigned short* smem)
{
  unsigned short* Wsw = smem;
  unsigned short* xsw = smem + 16384;
  int t = threadIdx.x;
  int spb = S >> 7;
  int n  = blk / spb;
  int s0 = (blk % spb) << 7;

  #pragma unroll
  for (int k = 0; k < 16; ++k) {
    int f4 = t + (k << 8);
    int o = f4 >> 5, cq = f4 & 31;
    float4 wq = *(const float4*)(W + (size_t)o * 128 + cq * 4);
    union { unsigned q[2]; s4v v; } hv;
    asm("v_cvt_pk_bf16_f32 %0, %1, %2" : "=v"(hv.q[0]) : "v"(wq.x), "v"(wq.y));
    asm("v_cvt_pk_bf16_f32 %0, %1, %2" : "=v"(hv.q[1]) : "v"(wq.z), "v"(wq.w));
    *(s4v*)(Wsw + (o * 16 + ((cq >> 1) ^ (o & 7))) * 8 + (cq & 1) * 4) = hv.v;
  }
  int sl = t & 127, coh = t >> 7;
  for (int co = coh; co < 16; co += 2) {
    const float* xb = x + (size_t)(n * 128 + co * 8) * S + s0 + sl;
    const float* aa = ab + n * 128 + co * 8;
    const float* bb = aa + 1024;
    float f[8];
    #pragma unroll
    for (int e = 0; e < 8; ++e) f[e] = fmaf(xb[(size_t)e * S], aa[e], bb[e]);
    union { unsigned q[4]; s8v v; } xv;
    #pragma unroll
    for (int e = 0; e < 4; ++e)
      asm("v_cvt_pk_bf16_f32 %0, %1, %2" : "=v"(xv.q[e]) : "v"(f[2*e]), "v"(f[2*e+1]));
    *(s8v*)(xsw + (co * 128 + sl) * 8) = xv.v;
  }
  __syncthreads();

  int lane = t & 63, w = t >> 6;
  int l31 = lane & 31, h = lane >> 5;
  int wo = (w & 1) << 6, wsp = (w >> 1) << 6;
  f16v acc00 = {}, acc01 = {}, acc10 = {}, acc11 = {};
  #pragma unroll
  for (int reg = 0; reg < 16; ++reg) {
    int rm = (reg & 3) + ((reg >> 2) << 3) + (h << 2);
    float b0 = bias[wo + rm], b1 = bias[wo + 32 + rm];
    acc00[reg] = b0; acc01[reg] = b0; acc10[reg] = b1; acc11[reg] = b1;
  }
  const s8v* Wv = (const s8v*)Wsw;
  const s8v* Xv = (const s8v*)xsw;
  int o0 = wo + l31, o1 = wo + 32 + l31;
  #pragma unroll
  for (int cs = 0; cs < 8; ++cs) {
    int kk = cs * 2 + h;
    s8v a0 = Wv[o0 * 16 + (kk ^ (o0 & 7))];
    s8v a1 = Wv[o1 * 16 + (kk ^ (o1 & 7))];
    s8v b0 = Xv[kk * 128 + wsp + l31];
    s8v b1 = Xv[kk * 128 + wsp + 32 + l31];
    acc00 = __builtin_amdgcn_mfma_f32_32x32x16_bf16(a0, b0, acc00, 0, 0, 0);
    acc01 = __builtin_amdgcn_mfma_f32_32x32x16_bf16(a0, b1, acc01, 0, 0, 0);
    acc10 = __builtin_amdgcn_mfma_f32_32x32x16_bf16(a1, b0, acc10, 0, 0, 0);
    acc11 = __builtin_amdgcn_mfma_f32_32x32x16_bf16(a1, b1, acc11, 0, 0, 0);
  }
  __syncthreads();
  unsigned short* ot = smem; // [128][132]
  #pragma unroll
  for (int reg = 0; reg < 16; ++reg) {
    int rm = (reg & 3) + ((reg >> 2) << 3) + (h << 2);
    ot[(wo + rm) * 132 + wsp + l31]           = f2bf(acc00[reg] * outScale);
    ot[(wo + rm) * 132 + wsp + 32 + l31]      = f2bf(acc01[reg] * outScale);
    ot[(wo + 32 + rm) * 132 + wsp + l31]      = f2bf(acc10[reg] * outScale);
    ot[(wo + 32 + rm) * 132 + wsp + 32 + l31] = f2bf(acc11[reg] * outScale);
  }
  __syncthreads();
  if (!vt_mode) {
    int d = t & 31;
    for (int i = 0; i < 64; ++i) {
      int idx2 = (t >> 5) + (i << 3);
      int s = idx2 & 127, ohi_ = idx2 >> 7;
      po[((size_t)(n * 4 + ohi_) * S + s0 + s) * 32 + d] = ot[(ohi_ * 32 + d) * 132 + s];
    }
  } else {
    int s = t & 127;
    for (int i = 0; i < 64; ++i) {
      int rr = (t >> 7) + i * 2;
      po[((size_t)(n * 4 + (rr >> 5)) * 32 + (rr & 31)) * S + s0 + s] = ot[rr * 132 + s];
    }
  }
}

__global__ __launch_bounds__(256) void convs_k(
    const float* __restrict__ q_src, const float* __restrict__ qab,
    const float* __restrict__ Wq, const float* __restrict__ bq, unsigned short* __restrict__ qhb,
    const float* __restrict__ knp, const float* __restrict__ kab,
    const float* __restrict__ Wk, const float* __restrict__ bk, unsigned short* __restrict__ khb,
    const float* __restrict__ vnp, const float* __restrict__ vab,
    const float* __restrict__ Wv, const float* __restrict__ bv, unsigned short* __restrict__ vtb,
    float qscale)
{
  __shared__ __align__(16) unsigned short smem[32768];
  int b = blockIdx.x;
  if (b < 256)      conv_body(b,       q_src, qab, Wq, bq, qhb, 4096, qscale, 0, smem);
  else if (b < 320) conv_body(b - 256, knp,   kab, Wk, bk, khb, 1024, 1.0f,   0, smem);
  else              conv_body(b - 320, vnp,   vab, Wv, bv, vtb, 1024, 1.0f,   1, smem);
}

// ---- final conv1x1 v2: f32 O in, W frags in VGPR from pre-split images, single X pass ----
// xo: [N][4096][128] f32. whi/wlo: frag images (16384 u16). out: [N][128][4096] f32.
// grid = N * 128 (32-spatial blocks).
__global__ __launch_bounds__(256) void conv_hilo_k(
    const float* __restrict__ xo, const unsigned short* __restrict__ whi,
    const unsigned short* __restrict__ wlo, const float* __restrict__ bias,
    float* __restrict__ out)
{
  __shared__ __align__(16) unsigned short Xh[4096], Xl[4096];
  int t = threadIdx.x;
  int lane = t & 63, w = t >> 6;
  int l31 = lane & 31, h = lane >> 5;
  int n = blockIdx.x >> 7, s0 = (blockIdx.x & 127) << 5;

  // all 16 W fragments up-front (L2-hot, 64 VGPR)
  int ol = w * 32 + l31;
  const s8v* WH = (const s8v*)whi;
  const s8v* WL = (const s8v*)wlo;
  s8v ah[8], al[8];
  #pragma unroll
  for (int cs = 0; cs < 8; ++cs) {
    int kk = cs * 2 + h;
    int ia = ol * 16 + (kk ^ (ol & 7));
    ah[cs] = WH[ia];
    al[cs] = WL[ia];
  }

  // stage X (f32 -> hi/lo bf16), layout [c-oct][s] 16B units, XOR swizzle
  #pragma unroll
  for (int i = 0; i < 2; ++i) {
    int co = t & 15, sl = (t >> 4) + i * 16;
    const float* xp = xo + (((size_t)(n * 4096 + s0 + sl)) << 7) + co * 8;
    float4 A = *(const float4*)xp;
    float4 B = *(const float4*)(xp + 4);
    float f[8] = {A.x, A.y, A.z, A.w, B.x, B.y, B.z, B.w};
    union { unsigned q[4]; s8v v; } H, L;
    #pragma unroll
    for (int e = 0; e < 4; ++e) {
      unsigned hp;
      asm("v_cvt_pk_bf16_f32 %0, %1, %2" : "=v"(hp) : "v"(f[2*e]), "v"(f[2*e+1]));
      H.q[e] = hp;
      float h0 = __uint_as_float(hp << 16);
      float h1 = __uint_as_float(hp & 0xFFFF0000u);
      float l0 = f[2*e] - h0, l1 = f[2*e+1] - h1;
      asm("v_cvt_pk_bf16_f32 %0, %1, %2" : "=v"(L.q[e]) : "v"(l0), "v"(l1));
    }
    int dst = ((co * 32 + sl) * 8) ^ ((co & 7) << 3);
    *(s8v*)(Xh + dst) = H.v;
    *(s8v*)(Xl + dst) = L.v;
  }
  __syncthreads();

  f16v acc;
  #pragma unroll
  for (int reg = 0; reg < 16; ++reg) {
    int rm = (reg & 3) + ((reg >> 2) << 3) + (h << 2);
    acc[reg] = bias[w * 32 + rm];
  }
  #pragma unroll
  for (int cs = 0; cs < 8; ++cs) {
    int kk = cs * 2 + h;
    int ix = ((kk * 32 + l31) * 8) ^ ((kk & 7) << 3);
    s8v bh = *(const s8v*)(Xh + ix);
    s8v bl = *(const s8v*)(Xl + ix);
    acc = __builtin_amdgcn_mfma_f32_32x32x16_bf16(ah[cs], bh, acc, 0, 0, 0);
    acc = __builtin_amdgcn_mfma_f32_32x32x16_bf16(ah[cs], bl, acc, 0, 0, 0);
    acc = __builtin_amdgcn_mfma_f32_32x32x16_bf16(al[cs], bh, acc, 0, 0, 0);
  }
  #pragma unroll
  for (int reg = 0; reg < 16; ++reg) {
    int rm = (reg & 3) + ((reg >> 2) << 3) + (h << 2);
    out[(size_t)(n * 128 + w * 32 + rm) * 4096 + s0 + l31] = acc[reg];
  }
}

// ------------- fused attention: dbuf + direct-Q + f32-O epilogue -------------
// qh: [N*4][4096][32] bf16 (pre-scaled by SCALE*log2e). kh: [N*4][1024][32].
// vt: [N*4][32][1024].  obuf: [N][4096][128] f32.
__global__ __launch_bounds__(256, 4) void attn_k(
    const unsigned short* __restrict__ qh, const unsigned short* __restrict__ kh,
    const unsigned short* __restrict__ vt, float* __restrict__ obuf)
{
  __shared__ __align__(16) unsigned short Klds[2][2048];
  __shared__ __align__(16) unsigned short Vlds[2][2048];
  __shared__ float linv[128];
  int t = threadIdx.x;
  int lane = t & 63, w = t >> 6;
  int l31 = lane & 31, h = lane >> 5;
  int blk = blockIdx.x;
  int nh = blk & 31, qb = blk >> 5;

  const unsigned short* qp = qh + (((size_t)nh * 4096 + qb * 128 + w * 32 + l31) << 5);
  s8v qf0 = *(const s8v*)(qp + h * 8);
  s8v qf1 = *(const s8v*)(qp + (2 + h) * 8);

  size_t kvb = (size_t)nh << 15;
  const unsigned short* kg = kh + kvb + ((t >> 2) << 5) + ((t & 3) << 3);
  const unsigned short* vg = vt + kvb + ((size_t)(t >> 3) << 10) + ((t & 7) << 3);
  int ku = ((t >> 2) << 2) + ((t & 3) ^ ((t >> 3) & 3));
  int vu = ((t >> 3) << 3) + ((t & 7) ^ ((t >> 3) & 7));

  s8v rk = *(const s8v*)kg;
  s8v rv = *(const s8v*)vg;
  *(s8v*)&Klds[0][ku * 8] = rk;
  *(s8v*)&Vlds[0][vu * 8] = rv;

  const f16v fz = {};
  f16v oacc = fz;
  f2v lp0 = mk2(0.f, 0.f), lp1 = mk2(0.f, 0.f);
  int kx = (l31 >> 1) & 3;
  int vx = l31 & 7;

  #pragma unroll 2
  for (int tile = 0; tile < 16; ++tile) {
    int buf = tile & 1;
    __syncthreads();
    if (tile < 15) {
      int j0 = (tile + 1) << 6;
      rk = *(const s8v*)(kg + (size_t)j0 * 32);
      rv = *(const s8v*)(vg + j0);
    }
    const unsigned short* Kb = Klds[buf];
    const unsigned short* Vb = Vlds[buf];
    #pragma unroll
    for (int s = 0; s < 2; ++s) {
      int rb = s * 128 + l31 * 4;
      s8v kf0 = *(const s8v*)(Kb + ((rb + (h ^ kx)) << 3));
      s8v kf1 = *(const s8v*)(Kb + ((rb + ((2 + h) ^ kx)) << 3));
      __builtin_amdgcn_s_setprio(1);
      f16v sf = __builtin_amdgcn_mfma_f32_32x32x16_bf16(kf0, qf0, fz, 0, 0, 0);
      sf = __builtin_amdgcn_mfma_f32_32x32x16_bf16(kf1, qf1, sf, 0, 0, 0);
      __builtin_amdgcn_s_setprio(0);
      float p[16];
      #pragma unroll
      for (int r = 0; r < 16; ++r) p[r] = fexp2(sf[r]);
      lp0 += mk2(p[0], p[1]);  lp1 += mk2(p[2], p[3]);
      lp0 += mk2(p[4], p[5]);  lp1 += mk2(p[6], p[7]);
      lp0 += mk2(p[8], p[9]);  lp1 += mk2(p[10], p[11]);
      lp0 += mk2(p[12], p[13]); lp1 += mk2(p[14], p[15]);
      unsigned c[8];
      #pragma unroll
      for (int q = 0; q < 8; ++q)
        asm("v_cvt_pk_bf16_f32 %0, %1, %2" : "=v"(c[q]) : "v"(p[2 * q]), "v"(p[2 * q + 1]));
      i2v s02 = __builtin_amdgcn_permlane32_swap((int)c[0], (int)c[2], false, false);
      i2v s13 = __builtin_amdgcn_permlane32_swap((int)c[1], (int)c[3], false, false);
      i2v s46 = __builtin_amdgcn_permlane32_swap((int)c[4], (int)c[6], false, false);
      i2v s57 = __builtin_amdgcn_permlane32_swap((int)c[5], (int)c[7], false, false);
      union { int u[4]; s8v v; } u0, u1;
      u0.u[0] = s02[0]; u0.u[1] = s13[0]; u0.u[2] = s02[1]; u0.u[3] = s13[1];
      u1.u[0] = s46[0]; u1.u[1] = s57[0]; u1.u[2] = s46[1]; u1.u[3] = s57[1];
      s8v vf0 = *(const s8v*)(Vb + ((l31 * 8 + ((s * 4 + h) ^ vx)) << 3));
      s8v vf1 = *(const s8v*)(Vb + ((l31 * 8 + ((s * 4 + 2 + h) ^ vx)) << 3));
      __builtin_amdgcn_s_setprio(1);
      oacc = __builtin_amdgcn_mfma_f32_32x32x16_bf16(u0.v, vf0, oacc, 0, 0, 0);
      oacc = __builtin_amdgcn_mfma_f32_32x32x16_bf16(u1.v, vf1, oacc, 0, 0, 0);
      __builtin_amdgcn_s_setprio(0);
    }
    if (tile < 15) {
      *(s8v*)&Klds[buf ^ 1][ku * 8] = rk;
      *(s8v*)&Vlds[buf ^ 1][vu * 8] = rv;
    }
  }

  float l_part = lp0[0] + lp0[1] + lp1[0] + lp1[1];
  float l_tot = l_part + __shfl_xor(l_part, 32);
  if (h == 0) linv[w * 32 + l31] = 1.0f / l_tot;
  __syncthreads();
  int n = nh >> 2, hh = nh & 3;
  size_t obase = (((size_t)n * 4096 + qb * 128) << 7) + hh * 32 + l31;
  #pragma unroll
  for (int reg = 0; reg < 16; ++reg) {
    int rm = (reg & 3) + ((reg >> 2) << 3) + (h << 2);
    obuf[obase + ((size_t)(w * 32 + rm) << 7)] = oacc[reg] * linv[w * 32 + rm];
  }
}

extern "C" void kernel_launch(void* const* d_in, const int* in_sizes, int n_in,
                              void* d_out, int out_size, void* d_ws, size_t ws_size,
                              hipStream_t stream)
{
  (void)in_sizes; (void)n_in; (void)out_size; (void)ws_size;
  const float* q_src = (const float*)d_in[0];
  const float* k_src = (const float*)d_in[1];
  const float* v_src = (const float*)d_in[2];
  const float* Wq = (const float*)d_in[3];
  const float* bq = (const float*)d_in[4];
  const float* Wk = (const float*)d_in[5];
  const float* bk = (const float*)d_in[6];
  const float* Wv = (const float*)d_in[7];
  const float* bv = (const float*)d_in[8];
  const float* Wp = (const float*)d_in[9];
  const float* bp = (const float*)d_in[10];
  const float* g_nq  = (const float*)d_in[11];
  const float* b_nq  = (const float*)d_in[12];
  const float* g_nk  = (const float*)d_in[13];
  const float* b_nk  = (const float*)d_in[14];
  const float* g_nv  = (const float*)d_in[15];
  const float* b_nv  = (const float*)d_in[16];
  const float* g_srk = (const float*)d_in[17];
  const float* b_srk = (const float*)d_in[18];
  const float* g_srv = (const float*)d_in[19];
  const float* b_srv = (const float*)d_in[20];

  unsigned short* qhb = (unsigned short*)d_ws;            // 8MB
  unsigned short* khb = qhb + 4194304;                    // 2MB
  unsigned short* vtb = khb + 1048576;                    // 2MB
  float* obuf = (float*)(vtb + 1048576);                  // 16MB
  float* knp  = obuf + 4194304;                           // 4MB
  float* vnp  = knp + 1048576;                            // 4MB
  float* qab  = vnp + 1048576;                            // 8KB
  float* kab  = qab + 2048;
  float* vab  = kab + 2048;
  unsigned short* whi = (unsigned short*)(vab + 2048);    // 32KB
  unsigned short* wlo = whi + 16384;

  const float QSCALE = 0.17677669529663688f * 1.44269504088896340f;

  prep_k<<<784, 256, 0, stream>>>(q_src, g_nq, b_nq,
                                  k_src, g_srk, b_srk, g_nk, b_nk,
                                  v_src, g_srv, b_srv, g_nv, b_nv,
                                  Wp, qab, kab, vab, knp, vnp, whi, wlo);
  convs_k<<<384, 256, 0, stream>>>(q_src, qab, Wq, bq, qhb,
                                   knp, kab, Wk, bk, khb,
                                   vnp, vab, Wv, bv, vtb, QSCALE);
  attn_k<<<1024, 256, 0, stream>>>(qhb, khb, vtb, obuf);
  conv_hilo_k<<<1024, 256, 0, stream>>>(obuf, whi, wlo, bp, (float*)d_out);
}

// Round 7
// 66.424 us; speedup vs baseline: 2.2878x; 1.0601x over previous
//
#include <hip/hip_runtime.h>

typedef __attribute__((ext_vector_type(8)))  short s8v;
typedef __attribute__((ext_vector_type(4)))  short s4v;
typedef __attribute__((ext_vector_type(16))) float f16v;
typedef __attribute__((ext_vector_type(2)))  int   i2v;
typedef __attribute__((ext_vector_type(2)))  float f2v;

__device__ __forceinline__ unsigned short f2bf(float f) {
  union { float f; unsigned u; } v; v.f = f;
  unsigned r = v.u + 0x7FFFu + ((v.u >> 16) & 1u);
  return (unsigned short)(r >> 16);
}
__device__ __forceinline__ float bf2f(unsigned short b) {
  return __uint_as_float((unsigned)b << 16);
}
__device__ __forceinline__ float fexp2(float x) {
#if __has_builtin(__builtin_amdgcn_exp2f)
  return __builtin_amdgcn_exp2f(x);
#else
  return exp2f(x);
#endif
}
__device__ __forceinline__ f2v mk2(float a, float b) { f2v r; r[0] = a; r[1] = b; return r; }

// ---------------- prep bodies ----------------
__device__ __forceinline__ void gn_stats_body(
    int blk, const float* __restrict__ x, const float* __restrict__ gamma,
    const float* __restrict__ beta, float* __restrict__ ab, float* sh)
{
  int n = blk >> 5, g = blk & 31;
  int t = threadIdx.x; int cl = t >> 6, lane = t & 63;
  const float4* x4 = (const float4*)(x + (size_t)(n * 128 + g * 4 + cl) * 4096);
  float s = 0.f, ss = 0.f;
  #pragma unroll
  for (int j = 0; j < 16; ++j) {
    float4 v = x4[lane + 64 * j];
    s  += v.x + v.y + v.z + v.w;
    ss += v.x * v.x + v.y * v.y + v.z * v.z + v.w * v.w;
  }
  #pragma unroll
  for (int m = 32; m >= 1; m >>= 1) { s += __shfl_xor(s, m); ss += __shfl_xor(ss, m); }
  if (lane == 0) { sh[cl] = s; sh[4 + cl] = ss; }
  __syncthreads();
  if (t < 4) {
    float mu = (sh[0] + sh[1] + sh[2] + sh[3]) * (1.f / 16384.f);
    float e  = (sh[4] + sh[5] + sh[6] + sh[7]) * (1.f / 16384.f);
    float r  = rsqrtf(e - mu * mu + 1e-5f);
    int c = g * 4 + t;
    float al = gamma[c] * r;
    ab[n * 128 + c] = al;
    ab[1024 + n * 128 + c] = beta[c] - mu * al;
  }
}

__device__ __forceinline__ void pool_aff_body(
    int blk, const float* __restrict__ x,
    const float* __restrict__ g1, const float* __restrict__ b1,
    const float* __restrict__ g2, const float* __restrict__ b2,
    float* __restrict__ pooled, float* __restrict__ ab, float* sh)
{
  int n = blk >> 5, g = blk & 31;
  int t = threadIdx.x; int cl = t >> 6, lane = t & 63;
  int c = g * 4 + cl;
  const float* xb = x + (size_t)(n * 128 + c) * 4096;
  float* pb = pooled + (size_t)(n * 128 + c) * 1024;
  float s = 0.f, ss = 0.f;
  #pragma unroll
  for (int j = 0; j < 8; ++j) {
    int pp = (lane + 64 * j) * 2;
    int py = pp >> 5, px2 = pp & 31;
    const float* r0 = xb + py * 128 + px2 * 2;
    float4 A = *(const float4*)r0;
    float4 B = *(const float4*)(r0 + 64);
    float v0 = 0.25f * (A.x + A.y + B.x + B.y);
    float v1 = 0.25f * (A.z + A.w + B.z + B.w);
    float2 wv; wv.x = v0; wv.y = v1;
    *(float2*)(pb + pp) = wv;
    s += v0 + v1; ss += v0 * v0 + v1 * v1;
  }
  #pragma unroll
  for (int m = 32; m >= 1; m >>= 1) { s += __shfl_xor(s, m); ss += __shfl_xor(ss, m); }
  if (lane == 0) { sh[cl] = s; sh[4 + cl] = ss; }
  __syncthreads();
  if (t < 4) {
    float mu1 = (sh[0] + sh[1] + sh[2] + sh[3]) * (1.f / 4096.f);
    float e1  = (sh[4] + sh[5] + sh[6] + sh[7]) * (1.f / 4096.f);
    float r1  = rsqrtf(e1 - mu1 * mu1 + 1e-5f);
    float mzs = 0.f, e2s = 0.f;
    #pragma unroll
    for (int cc = 0; cc < 4; ++cc) {
      int ch = g * 4 + cc;
      float a = r1 * g1[ch];
      float d = b1[ch] - mu1 * a;
      float m = sh[cc] * (1.f / 1024.f);
      float q = sh[4 + cc] * (1.f / 1024.f);
      mzs += a * m + d;
      e2s += a * a * q + 2.f * a * d * m + d * d;
    }
    float mu2 = 0.25f * mzs;
    float r2  = rsqrtf(0.25f * e2s - mu2 * mu2 + 1e-5f);
    int ch = g * 4 + t;
    float a = r1 * g1[ch];
    float d = b1[ch] - mu1 * a;
    ab[n * 128 + ch] = a * r2 * g2[ch];
    ab[1024 + n * 128 + ch] = (d - mu2) * r2 * g2[ch] + b2[ch];
  }
}

__device__ __forceinline__ void wsplit_body(
    int b, const float* __restrict__ W, unsigned short* __restrict__ whi,
    unsigned short* __restrict__ wlo)
{
  int idx = b * 256 + threadIdx.x;
  #pragma unroll
  for (int k = 0; k < 4; ++k) {
    int f = idx + k * 4096;
    int o = f >> 7, c = f & 127;
    float v = W[f];
    unsigned short hb = f2bf(v);
    unsigned short lb = f2bf(v - bf2f(hb));
    int cq = c >> 2;
    int adr = (o * 16 + ((cq >> 1) ^ (o & 7))) * 8 + (cq & 1) * 4 + (c & 3);
    whi[adr] = hb; wlo[adr] = lb;
  }
}

__global__ __launch_bounds__(256) void prep_k(
    const float* __restrict__ q_src, const float* __restrict__ g_nq, const float* __restrict__ b_nq,
    const float* __restrict__ k_src, const float* __restrict__ g_srk, const float* __restrict__ b_srk,
    const float* __restrict__ g_nk, const float* __restrict__ b_nk,
    const float* __restrict__ v_src, const float* __restrict__ g_srv, const float* __restrict__ b_srv,
    const float* __restrict__ g_nv, const float* __restrict__ b_nv,
    const float* __restrict__ Wp,
    float* __restrict__ qab, float* __restrict__ kab, float* __restrict__ vab,
    float* __restrict__ knp, float* __restrict__ vnp,
    unsigned short* __restrict__ whi, unsigned short* __restrict__ wlo)
{
  __shared__ float sh[8];
  int b = blockIdx.x;
  if (b < 256) gn_stats_body(b, q_src, g_nq, b_nq, qab, sh);
  else if (b < 512) pool_aff_body(b - 256, k_src, g_srk, b_srk, g_nk, b_nk, knp, kab, sh);
  else if (b < 768) pool_aff_body(b - 512, v_src, g_srv, b_srv, g_nv, b_nv, vnp, vab, sh);
  else wsplit_body(b - 768, Wp, whi, wlo);
}

// ------- conv1x1 body with fused input affine (bf16 MFMA) -------
__device__ __forceinline__ void conv_body(
    int blk, const float* __restrict__ x, const float* __restrict__ ab,
    const float* __restrict__ W, const float* __restrict__ bias,
    unsigned short* __restrict__ po, int S, float outScale, int vt_mode,
    unsigned short* smem)
{
  unsigned short* Wsw = smem;
  unsigned short* xsw = smem + 16384;
  int t = threadIdx.x;
  int spb = S >> 7;
  int n  = blk / spb;
  int s0 = (blk % spb) << 7;

  #pragma unroll
  for (int k = 0; k < 16; ++k) {
    int f4 = t + (k << 8);
    int o = f4 >> 5, cq = f4 & 31;
    float4 wq = *(const float4*)(W + (size_t)o * 128 + cq * 4);
    union { unsigned q[2]; s4v v; } hv;
    asm("v_cvt_pk_bf16_f32 %0, %1, %2" : "=v"(hv.q[0]) : "v"(wq.x), "v"(wq.y));
    asm("v_cvt_pk_bf16_f32 %0, %1, %2" : "=v"(hv.q[1]) : "v"(wq.z), "v"(wq.w));
    *(s4v*)(Wsw + (o * 16 + ((cq >> 1) ^ (o & 7))) * 8 + (cq & 1) * 4) = hv.v;
  }
  int sl = t & 127, coh = t >> 7;
  for (int co = coh; co < 16; co += 2) {
    const float* xb = x + (size_t)(n * 128 + co * 8) * S + s0 + sl;
    const float* aa = ab + n * 128 + co * 8;
    const float* bb = aa + 1024;
    float f[8];
    #pragma unroll
    for (int e = 0; e < 8; ++e) f[e] = fmaf(xb[(size_t)e * S], aa[e], bb[e]);
    union { unsigned q[4]; s8v v; } xv;
    #pragma unroll
    for (int e = 0; e < 4; ++e)
      asm("v_cvt_pk_bf16_f32 %0, %1, %2" : "=v"(xv.q[e]) : "v"(f[2*e]), "v"(f[2*e+1]));
    *(s8v*)(xsw + (co * 128 + sl) * 8) = xv.v;
  }
  __syncthreads();

  int lane = t & 63, w = t >> 6;
  int l31 = lane & 31, h = lane >> 5;
  int wo = (w & 1) << 6, wsp = (w >> 1) << 6;
  f16v acc00 = {}, acc01 = {}, acc10 = {}, acc11 = {};
  #pragma unroll
  for (int reg = 0; reg < 16; ++reg) {
    int rm = (reg & 3) + ((reg >> 2) << 3) + (h << 2);
    float b0 = bias[wo + rm], b1 = bias[wo + 32 + rm];
    acc00[reg] = b0; acc01[reg] = b0; acc10[reg] = b1; acc11[reg] = b1;
  }
  const s8v* Wv = (const s8v*)Wsw;
  const s8v* Xv = (const s8v*)xsw;
  int o0 = wo + l31, o1 = wo + 32 + l31;
  #pragma unroll
  for (int cs = 0; cs < 8; ++cs) {
    int kk = cs * 2 + h;
    s8v a0 = Wv[o0 * 16 + (kk ^ (o0 & 7))];
    s8v a1 = Wv[o1 * 16 + (kk ^ (o1 & 7))];
    s8v b0 = Xv[kk * 128 + wsp + l31];
    s8v b1 = Xv[kk * 128 + wsp + 32 + l31];
    acc00 = __builtin_amdgcn_mfma_f32_32x32x16_bf16(a0, b0, acc00, 0, 0, 0);
    acc01 = __builtin_amdgcn_mfma_f32_32x32x16_bf16(a0, b1, acc01, 0, 0, 0);
    acc10 = __builtin_amdgcn_mfma_f32_32x32x16_bf16(a1, b0, acc10, 0, 0, 0);
    acc11 = __builtin_amdgcn_mfma_f32_32x32x16_bf16(a1, b1, acc11, 0, 0, 0);
  }
  __syncthreads();
  unsigned short* ot = smem; // [128][132]
  #pragma unroll
  for (int reg = 0; reg < 16; ++reg) {
    int rm = (reg & 3) + ((reg >> 2) << 3) + (h << 2);
    ot[(wo + rm) * 132 + wsp + l31]           = f2bf(acc00[reg] * outScale);
    ot[(wo + rm) * 132 + wsp + 32 + l31]      = f2bf(acc01[reg] * outScale);
    ot[(wo + 32 + rm) * 132 + wsp + l31]      = f2bf(acc10[reg] * outScale);
    ot[(wo + 32 + rm) * 132 + wsp + 32 + l31] = f2bf(acc11[reg] * outScale);
  }
  __syncthreads();
  if (!vt_mode) {
    unsigned* po32 = (unsigned*)po;
    int d2 = t & 15;
    for (int i = 0; i < 32; ++i) {
      int pr = (t >> 4) + (i << 4);          // 0..511
      int s = pr & 127, ohi_ = pr >> 7;
      unsigned lo = ot[(ohi_ * 32 + d2 * 2) * 132 + s];
      unsigned hi = ot[(ohi_ * 32 + d2 * 2 + 1) * 132 + s];
      po32[((size_t)(n * 4 + ohi_) * S + s0 + s) * 16 + d2] = lo | (hi << 16);
    }
  } else {
    unsigned* po32 = (unsigned*)po;
    const unsigned* ot32 = (const unsigned*)ot; // [128][66]
    int sp = t & 63;
    for (int i = 0; i < 32; ++i) {
      int rr = (t >> 6) + (i << 2);          // 0..127
      po32[((size_t)(n * 4 + (rr >> 5)) * 32 + (rr & 31)) * (S >> 1) + (s0 >> 1) + sp] =
          ot32[rr * 66 + sp];
    }
  }
}

__global__ __launch_bounds__(256) void convs_k(
    const float* __restrict__ q_src, const float* __restrict__ qab,
    const float* __restrict__ Wq, const float* __restrict__ bq, unsigned short* __restrict__ qhb,
    const float* __restrict__ knp, const float* __restrict__ kab,
    const float* __restrict__ Wk, const float* __restrict__ bk, unsigned short* __restrict__ khb,
    const float* __restrict__ vnp, const float* __restrict__ vab,
    const float* __restrict__ Wv, const float* __restrict__ bv, unsigned short* __restrict__ vtb,
    float qscale)
{
  __shared__ __align__(16) unsigned short smem[32768];
  int b = blockIdx.x;
  if (b < 256)      conv_body(b,       q_src, qab, Wq, bq, qhb, 4096, qscale, 0, smem);
  else if (b < 320) conv_body(b - 256, knp,   kab, Wk, bk, khb, 1024, 1.0f,   0, smem);
  else              conv_body(b - 320, vnp,   vab, Wv, bv, vtb, 1024, 1.0f,   1, smem);
}

// ---- final conv1x1: f32 O in, W frags in VGPR, single X pass ----
__global__ __launch_bounds__(256) void conv_hilo_k(
    const float* __restrict__ xo, const unsigned short* __restrict__ whi,
    const unsigned short* __restrict__ wlo, const float* __restrict__ bias,
    float* __restrict__ out)
{
  __shared__ __align__(16) unsigned short Xh[4096], Xl[4096];
  int t = threadIdx.x;
  int lane = t & 63, w = t >> 6;
  int l31 = lane & 31, h = lane >> 5;
  int n = blockIdx.x >> 7, s0 = (blockIdx.x & 127) << 5;

  int ol = w * 32 + l31;
  const s8v* WH = (const s8v*)whi;
  const s8v* WL = (const s8v*)wlo;
  s8v ah[8], al[8];
  #pragma unroll
  for (int cs = 0; cs < 8; ++cs) {
    int kk = cs * 2 + h;
    int ia = ol * 16 + (kk ^ (ol & 7));
    ah[cs] = WH[ia];
    al[cs] = WL[ia];
  }

  #pragma unroll
  for (int i = 0; i < 2; ++i) {
    int co = t & 15, sl = (t >> 4) + i * 16;
    const float* xp = xo + (((size_t)(n * 4096 + s0 + sl)) << 7) + co * 8;
    float4 A = *(const float4*)xp;
    float4 B = *(const float4*)(xp + 4);
    float f[8] = {A.x, A.y, A.z, A.w, B.x, B.y, B.z, B.w};
    union { unsigned q[4]; s8v v; } H, L;
    #pragma unroll
    for (int e = 0; e < 4; ++e) {
      unsigned hp;
      asm("v_cvt_pk_bf16_f32 %0, %1, %2" : "=v"(hp) : "v"(f[2*e]), "v"(f[2*e+1]));
      H.q[e] = hp;
      float h0 = __uint_as_float(hp << 16);
      float h1 = __uint_as_float(hp & 0xFFFF0000u);
      float l0 = f[2*e] - h0, l1 = f[2*e+1] - h1;
      asm("v_cvt_pk_bf16_f32 %0, %1, %2" : "=v"(L.q[e]) : "v"(l0), "v"(l1));
    }
    int dst = ((co * 32 + sl) * 8) ^ ((co & 7) << 3);
    *(s8v*)(Xh + dst) = H.v;
    *(s8v*)(Xl + dst) = L.v;
  }
  __syncthreads();

  f16v acc;
  #pragma unroll
  for (int reg = 0; reg < 16; ++reg) {
    int rm = (reg & 3) + ((reg >> 2) << 3) + (h << 2);
    acc[reg] = bias[w * 32 + rm];
  }
  #pragma unroll
  for (int cs = 0; cs < 8; ++cs) {
    int kk = cs * 2 + h;
    int ix = ((kk * 32 + l31) * 8) ^ ((kk & 7) << 3);
    s8v bh = *(const s8v*)(Xh + ix);
    s8v bl = *(const s8v*)(Xl + ix);
    acc = __builtin_amdgcn_mfma_f32_32x32x16_bf16(ah[cs], bh, acc, 0, 0, 0);
    acc = __builtin_amdgcn_mfma_f32_32x32x16_bf16(ah[cs], bl, acc, 0, 0, 0);
    acc = __builtin_amdgcn_mfma_f32_32x32x16_bf16(al[cs], bh, acc, 0, 0, 0);
  }
  #pragma unroll
  for (int reg = 0; reg < 16; ++reg) {
    int rm = (reg & 3) + ((reg >> 2) << 3) + (h << 2);
    out[(size_t)(n * 128 + w * 32 + rm) * 4096 + s0 + l31] = acc[reg];
  }
}

// ------------- fused attention v4: KVBLK=128, dbuf, split PV accumulators -------------
// qh: [N*4][4096][32] bf16 (pre-scaled). kh: [N*4][1024][32]. vt: [N*4][32][1024].
// obuf: [N][4096][128] f32.
__global__ __launch_bounds__(256, 4) void attn_k(
    const unsigned short* __restrict__ qh, const unsigned short* __restrict__ kh,
    const unsigned short* __restrict__ vt, float* __restrict__ obuf)
{
  __shared__ __align__(16) unsigned short Klds[2][4096];
  __shared__ __align__(16) unsigned short Vlds[2][4096];
  __shared__ float linv[128];
  int t = threadIdx.x;
  int lane = t & 63, w = t >> 6;
  int l31 = lane & 31, h = lane >> 5;
  int blk = blockIdx.x;
  int nh = blk & 31, qb = blk >> 5;

  const unsigned short* qp = qh + (((size_t)nh * 4096 + qb * 128 + w * 32 + l31) << 5);
  s8v qf0 = *(const s8v*)(qp + h * 8);
  s8v qf1 = *(const s8v*)(qp + (2 + h) * 8);

  size_t kvb = (size_t)nh << 15;
  // K: unit u -> row=u>>2 (0..127), oct=u&3. thread handles u=t and u=t+256.
  const unsigned short* kg = kh + kvb + ((t >> 2) << 5) + ((t & 3) << 3);
  // V: unit u -> d=u>>4 (0..31), koct=u&15. thread handles u=t and u=t+256.
  const unsigned short* vg = vt + kvb + ((size_t)(t >> 4) << 10) + ((t & 15) << 3);
  int ku = ((t >> 2) << 2) + ((t & 3) ^ ((t >> 3) & 3));
  int vu = ((t >> 4) << 4) + ((t & 15) ^ ((t >> 4) & 15));

  // prologue: stage tile 0 into buf 0
  s8v rk0 = *(const s8v*)kg;
  s8v rk1 = *(const s8v*)(kg + 2048);
  s8v rv0 = *(const s8v*)vg;
  s8v rv1 = *(const s8v*)(vg + 16384);
  *(s8v*)&Klds[0][ku * 8]        = rk0;
  *(s8v*)&Klds[0][ku * 8 + 2048] = rk1;
  *(s8v*)&Vlds[0][vu * 8]        = rv0;
  *(s8v*)&Vlds[0][vu * 8 + 2048] = rv1;

  const f16v fz = {};
  f16v oa0 = fz, oa1 = fz;
  f2v lp0 = mk2(0.f, 0.f), lp1 = mk2(0.f, 0.f);
  int kx = (l31 >> 1) & 3;
  int vx = l31 & 15;

  for (int tile = 0; tile < 8; ++tile) {
    int buf = tile & 1;
    __syncthreads();
    if (tile < 7) {
      int j0 = (tile + 1) << 7;
      rk0 = *(const s8v*)(kg + (size_t)j0 * 32);
      rk1 = *(const s8v*)(kg + (size_t)j0 * 32 + 2048);
      rv0 = *(const s8v*)(vg + j0);
      rv1 = *(const s8v*)(vg + j0 + 16384);
    }
    const unsigned short* Kb = Klds[buf];
    const unsigned short* Vb = Vlds[buf];
    #pragma unroll
    for (int s2 = 0; s2 < 4; ++s2) {
      int rb = s2 * 128 + l31 * 4;
      s8v kf0 = *(const s8v*)(Kb + ((rb + (h ^ kx)) << 3));
      s8v kf1 = *(const s8v*)(Kb + ((rb + ((2 + h) ^ kx)) << 3));
      __builtin_amdgcn_s_setprio(1);
      f16v sf = __builtin_amdgcn_mfma_f32_32x32x16_bf16(kf0, qf0, fz, 0, 0, 0);
      sf = __builtin_amdgcn_mfma_f32_32x32x16_bf16(kf1, qf1, sf, 0, 0, 0);
      __builtin_amdgcn_s_setprio(0);
      float p[16];
      #pragma unroll
      for (int r = 0; r < 16; ++r) p[r] = fexp2(sf[r]);
      lp0 += mk2(p[0], p[1]);  lp1 += mk2(p[2], p[3]);
      lp0 += mk2(p[4], p[5]);  lp1 += mk2(p[6], p[7]);
      lp0 += mk2(p[8], p[9]);  lp1 += mk2(p[10], p[11]);
      lp0 += mk2(p[12], p[13]); lp1 += mk2(p[14], p[15]);
      unsigned c[8];
      #pragma unroll
      for (int q = 0; q < 8; ++q)
        asm("v_cvt_pk_bf16_f32 %0, %1, %2" : "=v"(c[q]) : "v"(p[2 * q]), "v"(p[2 * q + 1]));
      i2v s02 = __builtin_amdgcn_permlane32_swap((int)c[0], (int)c[2], false, false);
      i2v s13 = __builtin_amdgcn_permlane32_swap((int)c[1], (int)c[3], false, false);
      i2v s46 = __builtin_amdgcn_permlane32_swap((int)c[4], (int)c[6], false, false);
      i2v s57 = __builtin_amdgcn_permlane32_swap((int)c[5], (int)c[7], false, false);
      union { int u[4]; s8v v; } u0, u1;
      u0.u[0] = s02[0]; u0.u[1] = s13[0]; u0.u[2] = s02[1]; u0.u[3] = s13[1];
      u1.u[0] = s46[0]; u1.u[1] = s57[0]; u1.u[2] = s46[1]; u1.u[3] = s57[1];
      s8v vf0 = *(const s8v*)(Vb + ((l31 * 16 + ((s2 * 4 + h) ^ vx)) << 3));
      s8v vf1 = *(const s8v*)(Vb + ((l31 * 16 + ((s2 * 4 + 2 + h) ^ vx)) << 3));
      __builtin_amdgcn_s_setprio(1);
      if (s2 & 1) {
        oa1 = __builtin_amdgcn_mfma_f32_32x32x16_bf16(u0.v, vf0, oa1, 0, 0, 0);
        oa1 = __builtin_amdgcn_mfma_f32_32x32x16_bf16(u1.v, vf1, oa1, 0, 0, 0);
      } else {
        oa0 = __builtin_amdgcn_mfma_f32_32x32x16_bf16(u0.v, vf0, oa0, 0, 0, 0);
        oa0 = __builtin_amdgcn_mfma_f32_32x32x16_bf16(u1.v, vf1, oa0, 0, 0, 0);
      }
      __builtin_amdgcn_s_setprio(0);
    }
    if (tile < 7) {
      *(s8v*)&Klds[buf ^ 1][ku * 8]        = rk0;
      *(s8v*)&Klds[buf ^ 1][ku * 8 + 2048] = rk1;
      *(s8v*)&Vlds[buf ^ 1][vu * 8]        = rv0;
      *(s8v*)&Vlds[buf ^ 1][vu * 8 + 2048] = rv1;
    }
  }

  f16v oacc = oa0 + oa1;
  float l_part = lp0[0] + lp0[1] + lp1[0] + lp1[1];
  float l_tot = l_part + __shfl_xor(l_part, 32);
  if (h == 0) linv[w * 32 + l31] = 1.0f / l_tot;
  __syncthreads();
  int n = nh >> 2, hh = nh & 3;
  size_t obase = (((size_t)n * 4096 + qb * 128) << 7) + hh * 32 + l31;
  #pragma unroll
  for (int reg = 0; reg < 16; ++reg) {
    int rm = (reg & 3) + ((reg >> 2) << 3) + (h << 2);
    obuf[obase + ((size_t)(w * 32 + rm) << 7)] = oacc[reg] * linv[w * 32 + rm];
  }
}

extern "C" void kernel_launch(void* const* d_in, const int* in_sizes, int n_in,
                              void* d_out, int out_size, void* d_ws, size_t ws_size,
                              hipStream_t stream)
{
  (void)in_sizes; (void)n_in; (void)out_size; (void)ws_size;
  const float* q_src = (const float*)d_in[0];
  const float* k_src = (const float*)d_in[1];
  const float* v_src = (const float*)d_in[2];
  const float* Wq = (const float*)d_in[3];
  const float* bq = (const float*)d_in[4];
  const float* Wk = (const float*)d_in[5];
  const float* bk = (const float*)d_in[6];
  const float* Wv = (const float*)d_in[7];
  const float* bv = (const float*)d_in[8];
  const float* Wp = (const float*)d_in[9];
  const float* bp = (const float*)d_in[10];
  const float* g_nq  = (const float*)d_in[11];
  const float* b_nq  = (const float*)d_in[12];
  const float* g_nk  = (const float*)d_in[13];
  const float* b_nk  = (const float*)d_in[14];
  const float* g_nv  = (const float*)d_in[15];
  const float* b_nv  = (const float*)d_in[16];
  const float* g_srk = (const float*)d_in[17];
  const float* b_srk = (const float*)d_in[18];
  const float* g_srv = (const float*)d_in[19];
  const float* b_srv = (const float*)d_in[20];

  unsigned short* qhb = (unsigned short*)d_ws;            // 8MB
  unsigned short* khb = qhb + 4194304;                    // 2MB
  unsigned short* vtb = khb + 1048576;                    // 2MB
  float* obuf = (float*)(vtb + 1048576);                  // 16MB
  float* knp  = obuf + 4194304;                           // 4MB
  float* vnp  = knp + 1048576;                            // 4MB
  float* qab  = vnp + 1048576;                            // 8KB
  float* kab  = qab + 2048;
  float* vab  = kab + 2048;
  unsigned short* whi = (unsigned short*)(vab + 2048);    // 32KB
  unsigned short* wlo = whi + 16384;

  const float QSCALE = 0.17677669529663688f * 1.44269504088896340f;

  prep_k<<<784, 256, 0, stream>>>(q_src, g_nq, b_nq,
                                  k_src, g_srk, b_srk, g_nk, b_nk,
                                  v_src, g_srv, b_srv, g_nv, b_nv,
                                  Wp, qab, kab, vab, knp, vnp, whi, wlo);
  convs_k<<<384, 256, 0, stream>>>(q_src, qab, Wq, bq, qhb,
                                   knp, kab, Wk, bk, khb,
                                   vnp, vab, Wv, bv, vtb, QSCALE);
  attn_k<<<1024, 256, 0, stream>>>(qhb, khb, vtb, obuf);
  conv_hilo_k<<<1024, 256, 0, stream>>>(obuf, whi, wlo, bp, (float*)d_out);
}

// Round 8
// 63.325 us; speedup vs baseline: 2.3998x; 1.0489x over previous
//
#include <hip/hip_runtime.h>

typedef __attribute__((ext_vector_type(8)))  short s8v;
typedef __attribute__((ext_vector_type(4)))  short s4v;
typedef __attribute__((ext_vector_type(16))) float f16v;
typedef __attribute__((ext_vector_type(2)))  int   i2v;
typedef __attribute__((ext_vector_type(2)))  float f2v;

__device__ __forceinline__ unsigned short f2bf(float f) {
  union { float f; unsigned u; } v; v.f = f;
  unsigned r = v.u + 0x7FFFu + ((v.u >> 16) & 1u);
  return (unsigned short)(r >> 16);
}
__device__ __forceinline__ float bf2f(unsigned short b) {
  return __uint_as_float((unsigned)b << 16);
}
__device__ __forceinline__ float fexp2(float x) {
#if __has_builtin(__builtin_amdgcn_exp2f)
  return __builtin_amdgcn_exp2f(x);
#else
  return exp2f(x);
#endif
}
__device__ __forceinline__ f2v mk2(float a, float b) { f2v r; r[0] = a; r[1] = b; return r; }

// ---------------- prep bodies (unchanged from R7) ----------------
__device__ __forceinline__ void gn_stats_body(
    int blk, const float* __restrict__ x, const float* __restrict__ gamma,
    const float* __restrict__ beta, float* __restrict__ ab, float* sh)
{
  int n = blk >> 5, g = blk & 31;
  int t = threadIdx.x; int cl = t >> 6, lane = t & 63;
  const float4* x4 = (const float4*)(x + (size_t)(n * 128 + g * 4 + cl) * 4096);
  float s = 0.f, ss = 0.f;
  #pragma unroll
  for (int j = 0; j < 16; ++j) {
    float4 v = x4[lane + 64 * j];
    s  += v.x + v.y + v.z + v.w;
    ss += v.x * v.x + v.y * v.y + v.z * v.z + v.w * v.w;
  }
  #pragma unroll
  for (int m = 32; m >= 1; m >>= 1) { s += __shfl_xor(s, m); ss += __shfl_xor(ss, m); }
  if (lane == 0) { sh[cl] = s; sh[4 + cl] = ss; }
  __syncthreads();
  if (t < 4) {
    float mu = (sh[0] + sh[1] + sh[2] + sh[3]) * (1.f / 16384.f);
    float e  = (sh[4] + sh[5] + sh[6] + sh[7]) * (1.f / 16384.f);
    float r  = rsqrtf(e - mu * mu + 1e-5f);
    int c = g * 4 + t;
    float al = gamma[c] * r;
    ab[n * 128 + c] = al;
    ab[1024 + n * 128 + c] = beta[c] - mu * al;
  }
}

__device__ __forceinline__ void pool_aff_body(
    int blk, const float* __restrict__ x,
    const float* __restrict__ g1, const float* __restrict__ b1,
    const float* __restrict__ g2, const float* __restrict__ b2,
    float* __restrict__ pooled, float* __restrict__ ab, float* sh)
{
  int n = blk >> 5, g = blk & 31;
  int t = threadIdx.x; int cl = t >> 6, lane = t & 63;
  int c = g * 4 + cl;
  const float* xb = x + (size_t)(n * 128 + c) * 4096;
  float* pb = pooled + (size_t)(n * 128 + c) * 1024;
  float s = 0.f, ss = 0.f;
  #pragma unroll
  for (int j = 0; j < 8; ++j) {
    int pp = (lane + 64 * j) * 2;
    int py = pp >> 5, px2 = pp & 31;
    const float* r0 = xb + py * 128 + px2 * 2;
    float4 A = *(const float4*)r0;
    float4 B = *(const float4*)(r0 + 64);
    float v0 = 0.25f * (A.x + A.y + B.x + B.y);
    float v1 = 0.25f * (A.z + A.w + B.z + B.w);
    float2 wv; wv.x = v0; wv.y = v1;
    *(float2*)(pb + pp) = wv;
    s += v0 + v1; ss += v0 * v0 + v1 * v1;
  }
  #pragma unroll
  for (int m = 32; m >= 1; m >>= 1) { s += __shfl_xor(s, m); ss += __shfl_xor(ss, m); }
  if (lane == 0) { sh[cl] = s; sh[4 + cl] = ss; }
  __syncthreads();
  if (t < 4) {
    float mu1 = (sh[0] + sh[1] + sh[2] + sh[3]) * (1.f / 4096.f);
    float e1  = (sh[4] + sh[5] + sh[6] + sh[7]) * (1.f / 4096.f);
    float r1  = rsqrtf(e1 - mu1 * mu1 + 1e-5f);
    float mzs = 0.f, e2s = 0.f;
    #pragma unroll
    for (int cc = 0; cc < 4; ++cc) {
      int ch = g * 4 + cc;
      float a = r1 * g1[ch];
      float d = b1[ch] - mu1 * a;
      float m = sh[cc] * (1.f / 1024.f);
      float q = sh[4 + cc] * (1.f / 1024.f);
      mzs += a * m + d;
      e2s += a * a * q + 2.f * a * d * m + d * d;
    }
    float mu2 = 0.25f * mzs;
    float r2  = rsqrtf(0.25f * e2s - mu2 * mu2 + 1e-5f);
    int ch = g * 4 + t;
    float a = r1 * g1[ch];
    float d = b1[ch] - mu1 * a;
    ab[n * 128 + ch] = a * r2 * g2[ch];
    ab[1024 + n * 128 + ch] = (d - mu2) * r2 * g2[ch] + b2[ch];
  }
}

__device__ __forceinline__ void wsplit_body(
    int b, const float* __restrict__ W, unsigned short* __restrict__ whi,
    unsigned short* __restrict__ wlo)
{
  int idx = b * 256 + threadIdx.x;
  #pragma unroll
  for (int k = 0; k < 4; ++k) {
    int f = idx + k * 4096;
    int o = f >> 7, c = f & 127;
    float v = W[f];
    unsigned short hb = f2bf(v);
    unsigned short lb = f2bf(v - bf2f(hb));
    int cq = c >> 2;
    int adr = (o * 16 + ((cq >> 1) ^ (o & 7))) * 8 + (cq & 1) * 4 + (c & 3);
    whi[adr] = hb; wlo[adr] = lb;
  }
}

__global__ __launch_bounds__(256) void prep_k(
    const float* __restrict__ q_src, const float* __restrict__ g_nq, const float* __restrict__ b_nq,
    const float* __restrict__ k_src, const float* __restrict__ g_srk, const float* __restrict__ b_srk,
    const float* __restrict__ g_nk, const float* __restrict__ b_nk,
    const float* __restrict__ v_src, const float* __restrict__ g_srv, const float* __restrict__ b_srv,
    const float* __restrict__ g_nv, const float* __restrict__ b_nv,
    const float* __restrict__ Wp,
    float* __restrict__ qab, float* __restrict__ kab, float* __restrict__ vab,
    float* __restrict__ knp, float* __restrict__ vnp,
    unsigned short* __restrict__ whi, unsigned short* __restrict__ wlo)
{
  __shared__ float sh[8];
  int b = blockIdx.x;
  if (b < 256) gn_stats_body(b, q_src, g_nq, b_nq, qab, sh);
  else if (b < 512) pool_aff_body(b - 256, k_src, g_srk, b_srk, g_nk, b_nk, knp, kab, sh);
  else if (b < 768) pool_aff_body(b - 512, v_src, g_srv, b_srv, g_nv, b_nv, vnp, vab, sh);
  else wsplit_body(b - 768, Wp, whi, wlo);
}

// ------- conv1x1 body with fused input affine (unchanged from R7) -------
__device__ __forceinline__ void conv_body(
    int blk, const float* __restrict__ x, const float* __restrict__ ab,
    const float* __restrict__ W, const float* __restrict__ bias,
    unsigned short* __restrict__ po, int S, float outScale, int vt_mode,
    unsigned short* smem)
{
  unsigned short* Wsw = smem;
  unsigned short* xsw = smem + 16384;
  int t = threadIdx.x;
  int spb = S >> 7;
  int n  = blk / spb;
  int s0 = (blk % spb) << 7;

  #pragma unroll
  for (int k = 0; k < 16; ++k) {
    int f4 = t + (k << 8);
    int o = f4 >> 5, cq = f4 & 31;
    float4 wq = *(const float4*)(W + (size_t)o * 128 + cq * 4);
    union { unsigned q[2]; s4v v; } hv;
    asm("v_cvt_pk_bf16_f32 %0, %1, %2" : "=v"(hv.q[0]) : "v"(wq.x), "v"(wq.y));
    asm("v_cvt_pk_bf16_f32 %0, %1, %2" : "=v"(hv.q[1]) : "v"(wq.z), "v"(wq.w));
    *(s4v*)(Wsw + (o * 16 + ((cq >> 1) ^ (o & 7))) * 8 + (cq & 1) * 4) = hv.v;
  }
  int sl = t & 127, coh = t >> 7;
  for (int co = coh; co < 16; co += 2) {
    const float* xb = x + (size_t)(n * 128 + co * 8) * S + s0 + sl;
    const float* aa = ab + n * 128 + co * 8;
    const float* bb = aa + 1024;
    float f[8];
    #pragma unroll
    for (int e = 0; e < 8; ++e) f[e] = fmaf(xb[(size_t)e * S], aa[e], bb[e]);
    union { unsigned q[4]; s8v v; } xv;
    #pragma unroll
    for (int e = 0; e < 4; ++e)
      asm("v_cvt_pk_bf16_f32 %0, %1, %2" : "=v"(xv.q[e]) : "v"(f[2*e]), "v"(f[2*e+1]));
    *(s8v*)(xsw + (co * 128 + sl) * 8) = xv.v;
  }
  __syncthreads();

  int lane = t & 63, w = t >> 6;
  int l31 = lane & 31, h = lane >> 5;
  int wo = (w & 1) << 6, wsp = (w >> 1) << 6;
  f16v acc00 = {}, acc01 = {}, acc10 = {}, acc11 = {};
  #pragma unroll
  for (int reg = 0; reg < 16; ++reg) {
    int rm = (reg & 3) + ((reg >> 2) << 3) + (h << 2);
    float b0 = bias[wo + rm], b1 = bias[wo + 32 + rm];
    acc00[reg] = b0; acc01[reg] = b0; acc10[reg] = b1; acc11[reg] = b1;
  }
  const s8v* Wv = (const s8v*)Wsw;
  const s8v* Xv = (const s8v*)xsw;
  int o0 = wo + l31, o1 = wo + 32 + l31;
  #pragma unroll
  for (int cs = 0; cs < 8; ++cs) {
    int kk = cs * 2 + h;
    s8v a0 = Wv[o0 * 16 + (kk ^ (o0 & 7))];
    s8v a1 = Wv[o1 * 16 + (kk ^ (o1 & 7))];
    s8v b0 = Xv[kk * 128 + wsp + l31];
    s8v b1 = Xv[kk * 128 + wsp + 32 + l31];
    acc00 = __builtin_amdgcn_mfma_f32_32x32x16_bf16(a0, b0, acc00, 0, 0, 0);
    acc01 = __builtin_amdgcn_mfma_f32_32x32x16_bf16(a0, b1, acc01, 0, 0, 0);
    acc10 = __builtin_amdgcn_mfma_f32_32x32x16_bf16(a1, b0, acc10, 0, 0, 0);
    acc11 = __builtin_amdgcn_mfma_f32_32x32x16_bf16(a1, b1, acc11, 0, 0, 0);
  }
  __syncthreads();
  unsigned short* ot = smem; // [128][132]
  #pragma unroll
  for (int reg = 0; reg < 16; ++reg) {
    int rm = (reg & 3) + ((reg >> 2) << 3) + (h << 2);
    ot[(wo + rm) * 132 + wsp + l31]           = f2bf(acc00[reg] * outScale);
    ot[(wo + rm) * 132 + wsp + 32 + l31]      = f2bf(acc01[reg] * outScale);
    ot[(wo + 32 + rm) * 132 + wsp + l31]      = f2bf(acc10[reg] * outScale);
    ot[(wo + 32 + rm) * 132 + wsp + 32 + l31] = f2bf(acc11[reg] * outScale);
  }
  __syncthreads();
  if (!vt_mode) {
    unsigned* po32 = (unsigned*)po;
    int d2 = t & 15;
    for (int i = 0; i < 32; ++i) {
      int pr = (t >> 4) + (i << 4);
      int s = pr & 127, ohi_ = pr >> 7;
      unsigned lo = ot[(ohi_ * 32 + d2 * 2) * 132 + s];
      unsigned hi = ot[(ohi_ * 32 + d2 * 2 + 1) * 132 + s];
      po32[((size_t)(n * 4 + ohi_) * S + s0 + s) * 16 + d2] = lo | (hi << 16);
    }
  } else {
    unsigned* po32 = (unsigned*)po;
    const unsigned* ot32 = (const unsigned*)ot; // [128][66]
    int sp = t & 63;
    for (int i = 0; i < 32; ++i) {
      int rr = (t >> 6) + (i << 2);
      po32[((size_t)(n * 4 + (rr >> 5)) * 32 + (rr & 31)) * (S >> 1) + (s0 >> 1) + sp] =
          ot32[rr * 66 + sp];
    }
  }
}

__global__ __launch_bounds__(256) void convs_k(
    const float* __restrict__ q_src, const float* __restrict__ qab,
    const float* __restrict__ Wq, const float* __restrict__ bq, unsigned short* __restrict__ qhb,
    const float* __restrict__ knp, const float* __restrict__ kab,
    const float* __restrict__ Wk, const float* __restrict__ bk, unsigned short* __restrict__ khb,
    const float* __restrict__ vnp, const float* __restrict__ vab,
    const float* __restrict__ Wv, const float* __restrict__ bv, unsigned short* __restrict__ vtb,
    float qscale)
{
  __shared__ __align__(16) unsigned short smem[32768];
  int b = blockIdx.x;
  if (b < 256)      conv_body(b,       q_src, qab, Wq, bq, qhb, 4096, qscale, 0, smem);
  else if (b < 320) conv_body(b - 256, knp,   kab, Wk, bk, khb, 1024, 1.0f,   0, smem);
  else              conv_body(b - 320, vnp,   vab, Wv, bv, vtb, 1024, 1.0f,   1, smem);
}

// ------- fused attention + output projection -------
// Block = (n, qb: 128 q-rows). 1024 threads = 16 waves: wave (hh = w&3, qr = w>>2).
// qh: [N*4][4096][32] bf16 (pre-scaled). kh: [N*4][1024][32]. vt: [N*4][32][1024].
// whi/wlo: Wp frag images. out: [N][128][4096] f32.
__global__ __launch_bounds__(1024) void attn_proj_k(
    const unsigned short* __restrict__ qh, const unsigned short* __restrict__ kh,
    const unsigned short* __restrict__ vt, const unsigned short* __restrict__ whi,
    const unsigned short* __restrict__ wlo, const float* __restrict__ bp,
    float* __restrict__ out)
{
  __shared__ __align__(16) unsigned char SM[67584]; // 64KB KV (aliased X) + 2KB linv
  unsigned short* S16 = (unsigned short*)SM;
  float* linvp = (float*)(SM + 65536);
  int t = threadIdx.x;
  int lane = t & 63, w = t >> 6;
  int l31 = lane & 31, h = lane >> 5;
  int hh = w & 3, qr = w >> 2;
  int blk = blockIdx.x;
  int n = blk >> 5, qb = blk & 31;

  // Q fragments (verbatim v3 per-wave geometry: 32 rows)
  const unsigned short* qp =
      qh + (((size_t)(n * 4 + hh) * 4096 + qb * 128 + qr * 32 + l31) << 5);
  s8v qf0 = *(const s8v*)(qp + h * 8);
  s8v qf1 = *(const s8v*)(qp + (2 + h) * 8);

  // per-head staging: thread t -> head sh_=t>>8, unit si=t&255 (v3 formulas per head)
  int sh_ = t >> 8, si = t & 255;
  size_t kvb = (size_t)(n * 4 + sh_) << 15;
  const unsigned short* kg = kh + kvb + ((si >> 2) << 5) + ((si & 3) << 3);
  const unsigned short* vg = vt + kvb + ((size_t)(si >> 3) << 10) + ((si & 7) << 3);
  int ku = (si & ~3) | ((si & 3) ^ ((si >> 3) & 3));
  int vu = (si & ~7) | ((si & 7) ^ ((si >> 3) & 7));

  // prologue: tile 0 -> buf 0
  s8v rk = *(const s8v*)kg;
  s8v rvv = *(const s8v*)vg;
  *(s8v*)(S16 + sh_ * 2048 + ku * 8) = rk;
  *(s8v*)(S16 + 16384 + sh_ * 2048 + vu * 8) = rvv;

  const f16v fz = {};
  f16v oacc = fz;
  f2v lp0 = mk2(0.f, 0.f), lp1 = mk2(0.f, 0.f);
  int kx = (l31 >> 1) & 3;
  int vx = l31 & 7;

  for (int tile = 0; tile < 16; ++tile) {
    int buf = tile & 1;
    __syncthreads();
    if (tile < 15) {
      int j = (tile + 1) << 6;
      rk = *(const s8v*)(kg + (size_t)j * 32);
      rvv = *(const s8v*)(vg + j);
    }
    const unsigned short* Kb = S16 + (buf * 4 + hh) * 2048;
    const unsigned short* Vb = S16 + 16384 + (buf * 4 + hh) * 2048;
    #pragma unroll
    for (int s = 0; s < 2; ++s) {
      int rb = s * 128 + l31 * 4;
      s8v kf0 = *(const s8v*)(Kb + ((rb + (h ^ kx)) << 3));
      s8v kf1 = *(const s8v*)(Kb + ((rb + ((2 + h) ^ kx)) << 3));
      __builtin_amdgcn_s_setprio(1);
      f16v sf = __builtin_amdgcn_mfma_f32_32x32x16_bf16(kf0, qf0, fz, 0, 0, 0);
      sf = __builtin_amdgcn_mfma_f32_32x32x16_bf16(kf1, qf1, sf, 0, 0, 0);
      __builtin_amdgcn_s_setprio(0);
      float p[16];
      #pragma unroll
      for (int r = 0; r < 16; ++r) p[r] = fexp2(sf[r]);
      lp0 += mk2(p[0], p[1]);  lp1 += mk2(p[2], p[3]);
      lp0 += mk2(p[4], p[5]);  lp1 += mk2(p[6], p[7]);
      lp0 += mk2(p[8], p[9]);  lp1 += mk2(p[10], p[11]);
      lp0 += mk2(p[12], p[13]); lp1 += mk2(p[14], p[15]);
      unsigned c[8];
      #pragma unroll
      for (int q = 0; q < 8; ++q)
        asm("v_cvt_pk_bf16_f32 %0, %1, %2" : "=v"(c[q]) : "v"(p[2 * q]), "v"(p[2 * q + 1]));
      i2v s02 = __builtin_amdgcn_permlane32_swap((int)c[0], (int)c[2], false, false);
      i2v s13 = __builtin_amdgcn_permlane32_swap((int)c[1], (int)c[3], false, false);
      i2v s46 = __builtin_amdgcn_permlane32_swap((int)c[4], (int)c[6], false, false);
      i2v s57 = __builtin_amdgcn_permlane32_swap((int)c[5], (int)c[7], false, false);
      union { int u[4]; s8v v; } u0, u1;
      u0.u[0] = s02[0]; u0.u[1] = s13[0]; u0.u[2] = s02[1]; u0.u[3] = s13[1];
      u1.u[0] = s46[0]; u1.u[1] = s57[0]; u1.u[2] = s46[1]; u1.u[3] = s57[1];
      s8v vf0 = *(const s8v*)(Vb + ((l31 * 8 + ((s * 4 + h) ^ vx)) << 3));
      s8v vf1 = *(const s8v*)(Vb + ((l31 * 8 + ((s * 4 + 2 + h) ^ vx)) << 3));
      __builtin_amdgcn_s_setprio(1);
      oacc = __builtin_amdgcn_mfma_f32_32x32x16_bf16(u0.v, vf0, oacc, 0, 0, 0);
      oacc = __builtin_amdgcn_mfma_f32_32x32x16_bf16(u1.v, vf1, oacc, 0, 0, 0);
      __builtin_amdgcn_s_setprio(0);
    }
    if (tile < 15) {
      *(s8v*)(S16 + ((buf ^ 1) * 4 + sh_) * 2048 + ku * 8) = rk;
      *(s8v*)(S16 + 16384 + ((buf ^ 1) * 4 + sh_) * 2048 + vu * 8) = rvv;
    }
  }

  // softmax denominators -> linv[head][row]
  float l_part = lp0[0] + lp0[1] + lp1[0] + lp1[1];
  float l_tot = l_part + __shfl_xor(l_part, 32);
  if (h == 0) linvp[hh * 128 + qr * 32 + l31] = 1.0f / l_tot;
  __syncthreads();  // KV reads done; linv visible; safe to alias KV region as X

  // write normalized O (hi/lo bf16) into LDS as conv B layout [ch-oct][row], XOR row^co
  unsigned short* Xh16 = S16;
  unsigned short* Xl16 = S16 + 16384;
  int ch = hh * 32 + l31, co = ch >> 3, el = ch & 7;
  #pragma unroll
  for (int reg = 0; reg < 16; ++reg) {
    int rm = (reg & 3) + ((reg >> 2) << 3) + (h << 2);
    int row = qr * 32 + rm;
    float val = oacc[reg] * linvp[hh * 128 + row];
    unsigned short hb = f2bf(val);
    unsigned short lb = f2bf(val - bf2f(hb));
    int xu = co * 128 + (row ^ co);
    Xh16[xu * 8 + el] = hb;
    Xl16[xu * 8 + el] = lb;
  }
  __syncthreads();

  // projection: wave (hh,qr) -> out channels [hh*32,+32) x spatial rows [qr*32,+32)
  int ol = hh * 32 + l31;
  const s8v* WH = (const s8v*)whi;
  const s8v* WL = (const s8v*)wlo;
  s8v ah[8], al[8];
  #pragma unroll
  for (int cs = 0; cs < 8; ++cs) {
    int kk = cs * 2 + h;
    int ia = ol * 16 + (kk ^ (ol & 7));
    ah[cs] = WH[ia];
    al[cs] = WL[ia];
  }
  f16v acc;
  #pragma unroll
  for (int reg = 0; reg < 16; ++reg) {
    int rm = (reg & 3) + ((reg >> 2) << 3) + (h << 2);
    acc[reg] = bp[hh * 32 + rm];
  }
  int srow = qr * 32 + l31;
  #pragma unroll
  for (int cs = 0; cs < 8; ++cs) {
    int kk = cs * 2 + h;
    int xu = kk * 128 + (srow ^ kk);
    s8v bh = *(const s8v*)(Xh16 + xu * 8);
    s8v bl = *(const s8v*)(Xl16 + xu * 8);
    acc = __builtin_amdgcn_mfma_f32_32x32x16_bf16(ah[cs], bh, acc, 0, 0, 0);
    acc = __builtin_amdgcn_mfma_f32_32x32x16_bf16(ah[cs], bl, acc, 0, 0, 0);
    acc = __builtin_amdgcn_mfma_f32_32x32x16_bf16(al[cs], bh, acc, 0, 0, 0);
  }
  #pragma unroll
  for (int reg = 0; reg < 16; ++reg) {
    int rm = (reg & 3) + ((reg >> 2) << 3) + (h << 2);
    out[(size_t)(n * 128 + hh * 32 + rm) * 4096 + qb * 128 + srow] = acc[reg];
  }
}

extern "C" void kernel_launch(void* const* d_in, const int* in_sizes, int n_in,
                              void* d_out, int out_size, void* d_ws, size_t ws_size,
                              hipStream_t stream)
{
  (void)in_sizes; (void)n_in; (void)out_size; (void)ws_size;
  const float* q_src = (const float*)d_in[0];
  const float* k_src = (const float*)d_in[1];
  const float* v_src = (const float*)d_in[2];
  const float* Wq = (const float*)d_in[3];
  const float* bq = (const float*)d_in[4];
  const float* Wk = (const float*)d_in[5];
  const float* bk = (const float*)d_in[6];
  const float* Wv = (const float*)d_in[7];
  const float* bv = (const float*)d_in[8];
  const float* Wp = (const float*)d_in[9];
  const float* bp = (const float*)d_in[10];
  const float* g_nq  = (const float*)d_in[11];
  const float* b_nq  = (const float*)d_in[12];
  const float* g_nk  = (const float*)d_in[13];
  const float* b_nk  = (const float*)d_in[14];
  const float* g_nv  = (const float*)d_in[15];
  const float* b_nv  = (const float*)d_in[16];
  const float* g_srk = (const float*)d_in[17];
  const float* b_srk = (const float*)d_in[18];
  const float* g_srv = (const float*)d_in[19];
  const float* b_srv = (const float*)d_in[20];

  unsigned short* qhb = (unsigned short*)d_ws;            // 8MB
  unsigned short* khb = qhb + 4194304;                    // 2MB
  unsigned short* vtb = khb + 1048576;                    // 2MB
  float* knp  = (float*)(vtb + 1048576);                  // 4MB
  float* vnp  = knp + 1048576;                            // 4MB
  float* qab  = vnp + 1048576;                            // 8KB
  float* kab  = qab + 2048;
  float* vab  = kab + 2048;
  unsigned short* whi = (unsigned short*)(vab + 2048);    // 32KB
  unsigned short* wlo = whi + 16384;

  const float QSCALE = 0.17677669529663688f * 1.44269504088896340f;

  prep_k<<<784, 256, 0, stream>>>(q_src, g_nq, b_nq,
                                  k_src, g_srk, b_srk, g_nk, b_nk,
                                  v_src, g_srv, b_srv, g_nv, b_nv,
                                  Wp, qab, kab, vab, knp, vnp, whi, wlo);
  convs_k<<<384, 256, 0, stream>>>(q_src, qab, Wq, bq, qhb,
                                   knp, kab, Wk, bk, khb,
                                   vnp, vab, Wv, bv, vtb, QSCALE);
  attn_proj_k<<<256, 1024, 0, stream>>>(qhb, khb, vtb, whi, wlo, bp, (float*)d_out);
}